// Round 14
// baseline (688.081 us; speedup 1.0000x reference)
//
#include <hip/hip_runtime.h>
#include <hip/hip_cooperative_groups.h>
#include <hip/hip_bf16.h>
#include <math.h>

namespace cg = cooperative_groups;

#define Bq   2048
#define Cq   8
#define Dq   768
#define NROW 16384
#define NTOT 32768
#define Nq   4096
#define TEMPq 0.07f
#define NKC  96

typedef __attribute__((ext_vector_type(8))) short bf16x8;
typedef __attribute__((ext_vector_type(4))) float f32x4;
typedef __attribute__((ext_vector_type(8))) _Float16 f16x8;

__device__ __hip_bfloat16 g_pooledb[(size_t)Nq * Dq];
__device__ __hip_bfloat16 g_Wb[(size_t)Dq * Dq];
__device__ float          g_f[(size_t)Nq * Dq];
__device__ short          g_fbt[(size_t)NKC * Nq * 8];
__device__ _Float16       g_simh[(size_t)Nq * Nq];
__device__ unsigned int   g_viol;
__device__ float          g_rowloss[Nq];

#define GLDS16(src, dst) __builtin_amdgcn_global_load_lds( \
    (const __attribute__((address_space(1))) void*)(src),  \
    (__attribute__((address_space(3))) void*)(dst), 16, 0, 0)

extern "C" __global__ void __launch_bounds__(512)
mega_kernel(const float* __restrict__ z, const float* __restrict__ query,
            const float* __restrict__ attn_temp, const float* __restrict__ W,
            const float* __restrict__ bias, float* __restrict__ out) {
    cg::grid_group grid = cg::this_grid();
    extern __shared__ short smem[];                  // 128 KiB, re-aliased per stage
    const int tid  = threadIdx.x;
    const int wave = tid >> 6, lane = tid & 63;
    const int bid  = blockIdx.x;                     // 0..255

    // ================= stage P: fused pool + W->bf16 =================
    {
        int tidg = bid * 512 + tid;
        if (tidg == 0) g_viol = 0u;
        for (int i = tidg; i < (Dq * Dq / 4); i += 256 * 512) {
            float4 v = ((const float4*)W)[i];
            short4 o;
            o.x = ((__hip_bfloat16_raw)__float2bfloat16(v.x)).x;
            o.y = ((__hip_bfloat16_raw)__float2bfloat16(v.y)).x;
            o.z = ((__hip_bfloat16_raw)__float2bfloat16(v.z)).x;
            o.w = ((__hip_bfloat16_raw)__float2bfloat16(v.w)).x;
            ((short4*)g_Wb)[i] = o;
        }
        const int gw = bid * 8 + wave;               // 0..2047
        const float invt = 1.f / attn_temp[0];
        float4 q4[3];
#pragma unroll
        for (int j = 0; j < 3; ++j) q4[j] = *(const float4*)(query + j * 256 + lane * 4);

        for (int ss = 0; ss < 2; ++ss) {
            int seg = gw * 2 + ss;                   // 0..4095
            int half = seg >> 11;
            int b    = seg & 2047;
            int baseRow = half * NROW + b * Cq;

            float4 v4[Cq][3];
            float s[Cq];
#pragma unroll
            for (int c = 0; c < Cq; ++c) {
                const float* zr = z + (size_t)(baseRow + c) * Dq;
                float acc = 0.f;
#pragma unroll
                for (int j = 0; j < 3; ++j) {
                    float4 vz = *(const float4*)(zr + j * 256 + lane * 4);
                    v4[c][j] = vz;
                    acc += vz.x * q4[j].x + vz.y * q4[j].y + vz.z * q4[j].z + vz.w * q4[j].w;
                }
#pragma unroll
                for (int o = 32; o > 0; o >>= 1) acc += __shfl_xor(acc, o, 64);
                s[c] = acc * invt;
            }
            float m = s[0];
#pragma unroll
            for (int c = 1; c < Cq; ++c) m = fmaxf(m, s[c]);
            float e[Cq], denom = 0.f;
#pragma unroll
            for (int c = 0; c < Cq; ++c) { e[c] = expf(s[c] - m); denom += e[c]; }
            float inv = 1.f / (denom + 1e-8f);
#pragma unroll
            for (int j = 0; j < 3; ++j) {
                float4 acc = {0.f, 0.f, 0.f, 0.f};
#pragma unroll
                for (int c = 0; c < Cq; ++c) {
                    acc.x += v4[c][j].x * e[c];
                    acc.y += v4[c][j].y * e[c];
                    acc.z += v4[c][j].z * e[c];
                    acc.w += v4[c][j].w * e[c];
                }
                short4 o;
                o.x = ((__hip_bfloat16_raw)__float2bfloat16(acc.x * inv)).x;
                o.y = ((__hip_bfloat16_raw)__float2bfloat16(acc.y * inv)).x;
                o.z = ((__hip_bfloat16_raw)__float2bfloat16(acc.z * inv)).x;
                o.w = ((__hip_bfloat16_raw)__float2bfloat16(acc.w * inv)).x;
                *(short4*)((short*)g_pooledb + (size_t)seg * Dq + j * 256 + lane * 4) = o;
            }
        }
    }
    __threadfence(); grid.sync(); __threadfence();

    // ================= stage F: f = pooled @ W^T + b (8 waves, 128x256 tile, 96 tiles) =================
    if (bid < 96) {
        short* lA = smem;                 // 128x32 = 4096 shorts
        short* lB = smem + 4096;          // 256x32 = 8192 shorts
        const int bm = (bid / 3) * 128;
        const int bn = (bid % 3) * 256;
        const int wm = wave >> 2, wn = wave & 3;     // 2 x 4 waves -> 64x64 each
        const short* A  = (const short*)g_pooledb;
        const short* Bt = (const short*)g_Wb;
        const int srow = lane >> 2, scol = (lane & 3) * 8;

        f32x4 acc[4][4];
#pragma unroll
        for (int m = 0; m < 4; ++m)
#pragma unroll
            for (int n = 0; n < 4; ++n) acc[m][n] = (f32x4){0.f, 0.f, 0.f, 0.f};

        for (int k0 = 0; k0 < Dq; k0 += 32) {
            GLDS16(A  + (size_t)(bm + wave * 16 + srow) * Dq + k0 + scol, lA + wave * 512);
            GLDS16(Bt + (size_t)(bn + wave * 16 + srow) * Dq + k0 + scol, lB + wave * 512);
            GLDS16(Bt + (size_t)(bn + 128 + wave * 16 + srow) * Dq + k0 + scol, lB + 4096 + wave * 512);
            __syncthreads();

            bf16x8 af[4], bfr[4];
#pragma unroll
            for (int m = 0; m < 4; ++m) {
                int row = wm * 64 + m * 16 + (lane & 15);
                af[m] = *(const bf16x8*)(lA + row * 32 + (lane >> 4) * 8);
            }
#pragma unroll
            for (int n = 0; n < 4; ++n) {
                int row = wn * 64 + n * 16 + (lane & 15);
                bfr[n] = *(const bf16x8*)(lB + row * 32 + (lane >> 4) * 8);
            }
#pragma unroll
            for (int m = 0; m < 4; ++m)
#pragma unroll
                for (int n = 0; n < 4; ++n)
                    acc[m][n] = __builtin_amdgcn_mfma_f32_16x16x32_bf16(af[m], bfr[n], acc[m][n], 0, 0, 0);
            __syncthreads();
        }
#pragma unroll
        for (int m = 0; m < 4; ++m) {
            int rowb = bm + wm * 64 + m * 16 + (lane >> 4) * 4;
#pragma unroll
            for (int n = 0; n < 4; ++n) {
                int col = bn + wn * 64 + n * 16 + (lane & 15);
                float bc = bias[col];
#pragma unroll
                for (int j = 0; j < 4; ++j)
                    g_f[(size_t)(rowb + j) * Dq + col] = acc[m][n][j] + bc;
            }
        }
    }
    __threadfence(); grid.sync(); __threadfence();

    // ================= stage N: row-normalize -> bf16 chunk-transposed =================
    {
        short (*rowbuf)[776] = (short(*)[776])smem;   // 16 x 776 shorts = 24832 B
        const int r0 = bid * 16;
        for (int rr = wave; rr < 16; rr += 8) {
            int row = r0 + rr;
            float v[12];
            float ss = 0.f;
#pragma unroll
            for (int j = 0; j < 12; ++j) { v[j] = g_f[(size_t)row * Dq + j * 64 + lane]; ss += v[j] * v[j]; }
#pragma unroll
            for (int o = 32; o > 0; o >>= 1) ss += __shfl_xor(ss, o, 64);
            float rn = 1.f / sqrtf(ss);
#pragma unroll
            for (int j = 0; j < 12; ++j)
                rowbuf[rr][j * 64 + lane] = ((__hip_bfloat16_raw)__float2bfloat16(v[j] * rn)).x;
        }
        __syncthreads();
#pragma unroll
        for (int i = 0; i < 3; ++i) {
            int idx = i * 512 + tid;                  // < 1536 = 96 chunks x 16 rows
            int ch = idx >> 4;
            int r  = idx & 15;
            bf16x8 val = *(const bf16x8*)&rowbuf[r][ch * 8];
            *(bf16x8*)&g_fbt[((size_t)ch * Nq + r0 + r) * 8] = val;
        }
        __syncthreads();
    }
    __threadfence(); grid.sync(); __threadfence();

    // ================= stage S: sim = fb @ fb^T (256^2 tile, dbuf, counted vmcnt) =================
    {
        short* As = smem;
        short* Bs = smem + 32768;
        const int wm = wave >> 2, wn = wave & 3;
        const int bm = (bid >> 4) * 256, bn = (bid & 15) * 256;
        const short* fbt = g_fbt;

        f32x4 acc[8][4];
#pragma unroll
        for (int mi = 0; mi < 8; ++mi)
#pragma unroll
            for (int ni = 0; ni < 4; ++ni) acc[mi][ni] = (f32x4){0.f, 0.f, 0.f, 0.f};

#define STAGE_SIM(b, kt_) do {                                                          \
    _Pragma("unroll")                                                                   \
    for (int i = 0; i < 4; ++i) {                                                       \
        GLDS16(fbt + ((size_t)((kt_) * 8 + wave) * Nq + bm + i * 64 + lane) * 8,        \
               As + ((b) * 2048 + wave * 256 + i * 64) * 8);                            \
        GLDS16(fbt + ((size_t)((kt_) * 8 + wave) * Nq + bn + i * 64 + lane) * 8,        \
               Bs + ((b) * 2048 + wave * 256 + i * 64) * 8);                            \
    }                                                                                   \
} while (0)

        STAGE_SIM(0, 0);

#pragma unroll 1
        for (int kt = 0; kt < 12; ++kt) {
            const int cur = kt & 1;
            if (kt < 11) {
                STAGE_SIM(cur ^ 1, kt + 1);
                asm volatile("s_waitcnt vmcnt(8)" ::: "memory");
            } else {
                asm volatile("s_waitcnt vmcnt(0)" ::: "memory");
            }
            __builtin_amdgcn_s_barrier();
            __builtin_amdgcn_sched_barrier(0);

#pragma unroll
            for (int ks = 0; ks < 2; ++ks) {
                bf16x8 af[8], bfr[4];
                const int kc = (ks * 4 + (lane >> 4)) * 256;
#pragma unroll
                for (int mi = 0; mi < 8; ++mi)
                    af[mi] = *(const bf16x8*)(As + (cur * 2048 + kc + wm * 128 + mi * 16 + (lane & 15)) * 8);
#pragma unroll
                for (int ni = 0; ni < 4; ++ni)
                    bfr[ni] = *(const bf16x8*)(Bs + (cur * 2048 + kc + wn * 64 + ni * 16 + (lane & 15)) * 8);
                __builtin_amdgcn_s_setprio(1);
#pragma unroll
                for (int mi = 0; mi < 8; ++mi)
#pragma unroll
                    for (int ni = 0; ni < 4; ++ni)
                        acc[mi][ni] = __builtin_amdgcn_mfma_f32_16x16x32_bf16(af[mi], bfr[ni], acc[mi][ni], 0, 0, 0);
                __builtin_amdgcn_s_setprio(0);
            }
            __builtin_amdgcn_sched_barrier(0);
            __builtin_amdgcn_s_barrier();
        }
#undef STAGE_SIM

        int vio = 0;
#pragma unroll
        for (int mi = 0; mi < 8; ++mi) {
            int rowb = bm + wm * 128 + mi * 16 + (lane >> 4) * 4;
#pragma unroll
            for (int ni = 0; ni < 4; ++ni) {
                int col = bn + wn * 64 + ni * 16 + (lane & 15);
#pragma unroll
                for (int j = 0; j < 4; ++j) {
                    float x = acc[mi][ni][j];
                    g_simh[(size_t)(rowb + j) * Nq + col] = (_Float16)x;
                    vio += (x > 0.9f) && ((((rowb + j) ^ col) & 2047) != 0);
                }
            }
        }
#pragma unroll
        for (int o = 32; o > 0; o >>= 1) vio += __shfl_xor(vio, o, 64);
        if (lane == 0 && vio > 0) atomicAdd(&g_viol, (unsigned int)vio);
        __syncthreads();
    }
    __threadfence(); grid.sync(); __threadfence();

    // ================= stage L: lse (2 waves/row, 4 rows/pass, 4 passes) =================
    {
        float* fsh = (float*)smem;        // smx[8] smn[8] sA[8] sB[8]
        int*   ish = (int*)(fsh + 32);    // scnt[8] sred[16] sC[8]
        const float invT = 1.0f / TEMPq;
        unsigned int viol = atomicAdd(&g_viol, 0u);
        long long total = (long long)Nq * 4094LL - (long long)viol;
        int k = (int)(total / 8192LL);
        if (k < 1) k = 1;
        const int rib = wave >> 1;        // 0..3
        const int p   = wave & 1;
        const int rp  = rib * 2 + p;

        for (int pass = 0; pass < 4; ++pass) {
            const int row_id = pass * 1024 + bid * 4 + rib;
            const _Float16* row = g_simh + (size_t)row_id * Nq;
            const int labi = row_id & 2047;

            float v[32];
            float mx = -1e30f, mn = 1e30f;
            int cnt = 0;
#pragma unroll
            for (int q = 0; q < 4; ++q) {
                int j0 = p * 2048 + q * 512 + lane * 8;
                f16x8 x8 = *(const f16x8*)(row + j0);
#pragma unroll
                for (int s = 0; s < 8; ++s) {
                    int jj = q * 8 + s;
                    int j  = j0 + s;
                    float xv = (float)x8[s];
                    bool sf = (xv <= 0.9f) && (((j ^ labi) & 2047) != 0);
                    float val = sf ? xv : -2.0f;
                    v[jj] = val;
                    mx = fmaxf(mx, val);
                    mn = fminf(mn, sf ? xv : 2.0f);
                    cnt += (int)__popcll(__ballot(sf));
                }
            }
#pragma unroll
            for (int o = 32; o > 0; o >>= 1) {
                mx = fmaxf(mx, __shfl_xor(mx, o, 64));
                mn = fminf(mn, __shfl_xor(mn, o, 64));
            }
            if (lane == 0) { fsh[rp] = mx; fsh[8 + rp] = mn; ish[rp] = cnt; }
            __syncthreads();
            mx  = fmaxf(fsh[rib * 2], fsh[rib * 2 + 1]);
            mn  = fminf(fsh[8 + rib * 2], fsh[8 + rib * 2 + 1]);
            cnt = ish[rib * 2] + ish[rib * 2 + 1];

            const float pos = (float)row[(row_id + Bq) & (Nq - 1)];
            const float mxs = (cnt > 0) ? mx : -10.0f;
            const float ml  = fmaxf(pos, mxs) * invT;

            float lo = mn - 1e-3f, hi = mx;
            int c_hi = 0;
            const bool need = (cnt > k);
            for (int it = 0; it < 12; ++it) {
                float mid = 0.5f * (lo + hi);
                int c = 0;
#pragma unroll
                for (int jj = 0; jj < 32; ++jj)
                    c += (int)__popcll(__ballot(v[jj] > mid));
                if (lane == 0) ish[8 + (it & 1) * 8 + rp] = c;
                __syncthreads();
                c = ish[8 + (it & 1) * 8 + rib * 2] + ish[8 + (it & 1) * 8 + rib * 2 + 1];
                if (need) { if (c > k) lo = mid; else { hi = mid; c_hi = c; } }
            }

            float shi = 0.f, st = 0.f; int nt = 0;
#pragma unroll
            for (int jj = 0; jj < 32; ++jj) {
                float x = v[jj];
                float ev = __expf(x * invT - ml);
                if (!need)       { if (x > -1.5f) shi += ev; }
                else if (x > hi) { shi += ev; }
                else if (x > lo) { st += ev; nt++; }
            }
#pragma unroll
            for (int o = 32; o > 0; o >>= 1) {
                shi += __shfl_xor(shi, o, 64);
                st  += __shfl_xor(st,  o, 64);
                nt  += __shfl_xor(nt,  o, 64);
            }
            if (lane == 0) { fsh[16 + rp] = shi; fsh[24 + rp] = st; ish[24 + rp] = nt; }
            __syncthreads();
            if (p == 0 && lane == 0) {
                float Shi = fsh[16 + rib * 2] + fsh[16 + rib * 2 + 1];
                float St  = fsh[24 + rib * 2] + fsh[24 + rib * 2 + 1];
                int   Nt  = ish[24 + rib * 2] + ish[24 + rib * 2 + 1];
                float S = __expf(pos * invT - ml) + Shi;
                if (need && c_hi < k && Nt > 0)
                    S += St * (float)(k - c_hi) / (float)Nt;
                g_rowloss[row_id] = (logf(S) + ml) - pos * invT;
            }
            __syncthreads();
        }
    }
    __threadfence(); grid.sync(); __threadfence();

    // ================= stage Z: final mean (block 0) =================
    if (bid == 0) {
        float s = 0.f;
        for (int i = tid; i < Nq; i += 512) s += g_rowloss[i];
        float* sm = (float*)smem;
        sm[tid] = s; __syncthreads();
        for (int o = 256; o > 0; o >>= 1) {
            if (tid < o) sm[tid] += sm[tid + o];
            __syncthreads();
        }
        if (tid == 0) out[0] = sm[0] / (float)Nq;
    }
}

extern "C" void kernel_launch(void* const* d_in, const int* in_sizes, int n_in,
                              void* d_out, int out_size, void* d_ws, size_t ws_size,
                              hipStream_t stream) {
    const float* z         = (const float*)d_in[0];
    const float* query     = (const float*)d_in[3];
    const float* attn_temp = (const float*)d_in[4];
    const float* W         = (const float*)d_in[5];
    const float* bias      = (const float*)d_in[6];
    float* out = (float*)d_out;

    void* kargs[] = { (void*)&z, (void*)&query, (void*)&attn_temp,
                      (void*)&W, (void*)&bias, (void*)&out };
    hipLaunchCooperativeKernel((const void*)mega_kernel, dim3(256), dim3(512),
                               kargs, 131072, stream);
}

// Round 15
// 112.526 us; speedup vs baseline: 6.1148x; 6.1148x over previous
//
#include <hip/hip_runtime.h>
#include <hip/hip_bf16.h>
#include <math.h>

#define Bq   2048
#define Cq   8
#define Dq   768
#define NROW 16384      // B*C per half
#define NTOT 32768      // 2*B*C
#define Nq   4096       // 2*B rows of f
#define TEMPq 0.07f
#define NKC  96         // 768/8 k-chunks of 8 bf16 (16 B)

typedef __attribute__((ext_vector_type(8))) short bf16x8;
typedef __attribute__((ext_vector_type(4))) float f32x4;
typedef __attribute__((ext_vector_type(8))) _Float16 f16x8;

// persistent device scratch (fully overwritten every call -> deterministic)
__device__ __hip_bfloat16 g_pooledb[(size_t)Nq * Dq];
__device__ __hip_bfloat16 g_Wb[(size_t)Dq * Dq];
__device__ float          g_f[(size_t)Nq * Dq];
__device__ short          g_fbt[(size_t)NKC * Nq * 8];   // [kc][row][8 bf16] chunk-transposed
__device__ _Float16       g_simh[(size_t)Nq * Nq];
__device__ unsigned int   g_viol;
__device__ float          g_rowloss[Nq];

#define GLDS16(src, dst) __builtin_amdgcn_global_load_lds( \
    (const __attribute__((address_space(1))) void*)(src),  \
    (__attribute__((address_space(3))) void*)(dst), 16, 0, 0)

// ---------- merged: [blocks 0..1023] fused pool, [1024..1599] W->bf16 ----------
__global__ __launch_bounds__(256) void prep_kernel(const float* __restrict__ z,
                                                   const float* __restrict__ query,
                                                   const float* __restrict__ attn_temp,
                                                   const float* __restrict__ W) {
    if (blockIdx.x >= 1024) {
        int i = (blockIdx.x - 1024) * 256 + threadIdx.x;
        if (i == 0) g_viol = 0u;
        float4 v = ((const float4*)W)[i];
        short4 o;
        o.x = ((__hip_bfloat16_raw)__float2bfloat16(v.x)).x;
        o.y = ((__hip_bfloat16_raw)__float2bfloat16(v.y)).x;
        o.z = ((__hip_bfloat16_raw)__float2bfloat16(v.z)).x;
        o.w = ((__hip_bfloat16_raw)__float2bfloat16(v.w)).x;
        ((short4*)g_Wb)[i] = o;
        return;
    }
    int seg  = (int)((blockIdx.x * blockDim.x + threadIdx.x) >> 6);
    int lane = threadIdx.x & 63;
    if (seg >= Nq) return;
    int half = seg >> 11;
    int b    = seg & 2047;
    int baseRow = half * NROW + b * Cq;
    float invt = 1.f / attn_temp[0];

    float4 q4[3];
#pragma unroll
    for (int j = 0; j < 3; ++j) q4[j] = *(const float4*)(query + j * 256 + lane * 4);

    float4 v4[Cq][3];
    float s[Cq];
#pragma unroll
    for (int c = 0; c < Cq; ++c) {
        const float* zr = z + (size_t)(baseRow + c) * Dq;
        float acc = 0.f;
#pragma unroll
        for (int j = 0; j < 3; ++j) {
            float4 vz = *(const float4*)(zr + j * 256 + lane * 4);
            v4[c][j] = vz;
            acc += vz.x * q4[j].x + vz.y * q4[j].y + vz.z * q4[j].z + vz.w * q4[j].w;
        }
#pragma unroll
        for (int o = 32; o > 0; o >>= 1) acc += __shfl_xor(acc, o, 64);
        s[c] = acc * invt;
    }
    float m = s[0];
#pragma unroll
    for (int c = 1; c < Cq; ++c) m = fmaxf(m, s[c]);
    float e[Cq], denom = 0.f;
#pragma unroll
    for (int c = 0; c < Cq; ++c) { e[c] = expf(s[c] - m); denom += e[c]; }
    float inv = 1.f / (denom + 1e-8f);
#pragma unroll
    for (int j = 0; j < 3; ++j) {
        float4 acc = {0.f, 0.f, 0.f, 0.f};
#pragma unroll
        for (int c = 0; c < Cq; ++c) {
            acc.x += v4[c][j].x * e[c];
            acc.y += v4[c][j].y * e[c];
            acc.z += v4[c][j].z * e[c];
            acc.w += v4[c][j].w * e[c];
        }
        short4 o;
        o.x = ((__hip_bfloat16_raw)__float2bfloat16(acc.x * inv)).x;
        o.y = ((__hip_bfloat16_raw)__float2bfloat16(acc.y * inv)).x;
        o.z = ((__hip_bfloat16_raw)__float2bfloat16(acc.z * inv)).x;
        o.w = ((__hip_bfloat16_raw)__float2bfloat16(acc.w * inv)).x;
        *(short4*)((short*)g_pooledb + (size_t)seg * Dq + j * 256 + lane * 4) = o;
    }
}

// ---------- f = pooled @ W^T + b via bf16 MFMA, 64x128 tile (384 blocks, occupancy fix) ----------
__global__ __launch_bounds__(256) void fw_mfma_kernel(const float* __restrict__ bias) {
    __shared__ short lA[64 * 32];     // 4 KB
    __shared__ short lB[128 * 32];    // 8 KB
    const int bm = blockIdx.y * 64;
    const int bn = blockIdx.x * 128;

    const int tid  = threadIdx.x;
    const int wave = tid >> 6, lane = tid & 63;
    const int wm = wave >> 1, wn = wave & 1;       // 2x2 wave grid; per-wave C: 32x64

    const short* A  = (const short*)g_pooledb;
    const short* Bt = (const short*)g_Wb;

    const int srow = lane >> 2;
    const int scol = (lane & 3) * 8;
    const int c0 = wave * 2, c1 = wave * 2 + 1;    // B chunks

    f32x4 acc[2][4];
#pragma unroll
    for (int m = 0; m < 2; ++m)
#pragma unroll
        for (int n = 0; n < 4; ++n) acc[m][n] = (f32x4){0.f, 0.f, 0.f, 0.f};

    for (int k0 = 0; k0 < Dq; k0 += 32) {
        GLDS16(A  + (size_t)(bm + wave * 16 + srow) * Dq + k0 + scol, lA + wave * 512);
        GLDS16(Bt + (size_t)(bn + c0 * 16 + srow) * Dq + k0 + scol, lB + c0 * 512);
        GLDS16(Bt + (size_t)(bn + c1 * 16 + srow) * Dq + k0 + scol, lB + c1 * 512);
        __syncthreads();

        bf16x8 af[2], bfr[4];
#pragma unroll
        for (int m = 0; m < 2; ++m) {
            int row = wm * 32 + m * 16 + (lane & 15);
            af[m] = *(const bf16x8*)(lA + row * 32 + (lane >> 4) * 8);
        }
#pragma unroll
        for (int n = 0; n < 4; ++n) {
            int row = wn * 64 + n * 16 + (lane & 15);
            bfr[n] = *(const bf16x8*)(lB + row * 32 + (lane >> 4) * 8);
        }
#pragma unroll
        for (int m = 0; m < 2; ++m)
#pragma unroll
            for (int n = 0; n < 4; ++n)
                acc[m][n] = __builtin_amdgcn_mfma_f32_16x16x32_bf16(af[m], bfr[n], acc[m][n], 0, 0, 0);
        __syncthreads();
    }

#pragma unroll
    for (int m = 0; m < 2; ++m) {
        int rowb = bm + wm * 32 + m * 16 + (lane >> 4) * 4;
#pragma unroll
        for (int n = 0; n < 4; ++n) {
            int col = bn + wn * 64 + n * 16 + (lane & 15);
            float bc = bias[col];
#pragma unroll
            for (int j = 0; j < 4; ++j)
                g_f[(size_t)(rowb + j) * Dq + col] = acc[m][n][j] + bc;
        }
    }
}

// ---------- row-normalize -> bf16, chunk-transposed store. 16 rows/block ----------
__global__ __launch_bounds__(256) void normalize_kernel() {
    __shared__ short rowbuf[16][776];
    const int tid = threadIdx.x;
    const int wave = tid >> 6, lane = tid & 63;
    const int r0 = blockIdx.x * 16;

    for (int rr = wave; rr < 16; rr += 4) {
        int row = r0 + rr;
        float v[12];
        float ss = 0.f;
#pragma unroll
        for (int j = 0; j < 12; ++j) { v[j] = g_f[(size_t)row * Dq + j * 64 + lane]; ss += v[j] * v[j]; }
#pragma unroll
        for (int o = 32; o > 0; o >>= 1) ss += __shfl_xor(ss, o, 64);
        float rn = 1.f / sqrtf(ss);
#pragma unroll
        for (int j = 0; j < 12; ++j)
            rowbuf[rr][j * 64 + lane] = ((__hip_bfloat16_raw)__float2bfloat16(v[j] * rn)).x;
    }
    __syncthreads();
#pragma unroll
    for (int i = 0; i < 6; ++i) {
        int idx = i * 256 + tid;
        int ch = idx >> 4;
        int r  = idx & 15;
        bf16x8 val = *(const bf16x8*)&rowbuf[r][ch * 8];
        *(bf16x8*)&g_fbt[((size_t)ch * Nq + r0 + r) * 8] = val;
    }
}

// ---------- sim = fb @ fb^T : 256^2 tile, 8 waves, BK=64, dbuf + counted vmcnt ----------
#define STAGE_SIM(b, kt_) do {                                                          \
    _Pragma("unroll")                                                                   \
    for (int i = 0; i < 4; ++i) {                                                       \
        GLDS16(fbt + ((size_t)((kt_) * 8 + wave) * Nq + bm + i * 64 + lane) * 8,        \
               As + ((b) * 2048 + wave * 256 + i * 64) * 8);                            \
        GLDS16(fbt + ((size_t)((kt_) * 8 + wave) * Nq + bn + i * 64 + lane) * 8,        \
               Bs + ((b) * 2048 + wave * 256 + i * 64) * 8);                            \
    }                                                                                   \
} while (0)

__global__ __launch_bounds__(512) void sim_mfma_kernel() {
    extern __shared__ short smem[];          // 128 KiB
    short* As = smem;
    short* Bs = smem + 32768;

    const int tid  = threadIdx.x;
    const int wave = tid >> 6, lane = tid & 63;
    const int wm = wave >> 2, wn = wave & 3;
    const int bm = blockIdx.y * 256, bn = blockIdx.x * 256;
    const short* fbt = g_fbt;

    f32x4 acc[8][4];
#pragma unroll
    for (int mi = 0; mi < 8; ++mi)
#pragma unroll
        for (int ni = 0; ni < 4; ++ni) acc[mi][ni] = (f32x4){0.f, 0.f, 0.f, 0.f};

    STAGE_SIM(0, 0);

#pragma unroll 1
    for (int kt = 0; kt < 12; ++kt) {
        const int cur = kt & 1;
        if (kt < 11) {
            STAGE_SIM(cur ^ 1, kt + 1);
            asm volatile("s_waitcnt vmcnt(8)" ::: "memory");
        } else {
            asm volatile("s_waitcnt vmcnt(0)" ::: "memory");
        }
        __builtin_amdgcn_s_barrier();
        __builtin_amdgcn_sched_barrier(0);

#pragma unroll
        for (int ks = 0; ks < 2; ++ks) {
            bf16x8 af[8], bfr[4];
            const int kc = (ks * 4 + (lane >> 4)) * 256;
#pragma unroll
            for (int mi = 0; mi < 8; ++mi)
                af[mi] = *(const bf16x8*)(As + (cur * 2048 + kc + wm * 128 + mi * 16 + (lane & 15)) * 8);
#pragma unroll
            for (int ni = 0; ni < 4; ++ni)
                bfr[ni] = *(const bf16x8*)(Bs + (cur * 2048 + kc + wn * 64 + ni * 16 + (lane & 15)) * 8);
            __builtin_amdgcn_s_setprio(1);
#pragma unroll
            for (int mi = 0; mi < 8; ++mi)
#pragma unroll
                for (int ni = 0; ni < 4; ++ni)
                    acc[mi][ni] = __builtin_amdgcn_mfma_f32_16x16x32_bf16(af[mi], bfr[ni], acc[mi][ni], 0, 0, 0);
            __builtin_amdgcn_s_setprio(0);
        }
        __builtin_amdgcn_sched_barrier(0);
        __builtin_amdgcn_s_barrier();
    }

    // epilogue: fp16 store (full matrix, no mirror) + violation count
    int vio = 0;
#pragma unroll
    for (int mi = 0; mi < 8; ++mi) {
        int rowb = bm + wm * 128 + mi * 16 + (lane >> 4) * 4;
#pragma unroll
        for (int ni = 0; ni < 4; ++ni) {
            int col = bn + wn * 64 + ni * 16 + (lane & 15);
#pragma unroll
            for (int j = 0; j < 4; ++j) {
                float x = acc[mi][ni][j];
                g_simh[(size_t)(rowb + j) * Nq + col] = (_Float16)x;
                vio += (x > 0.9f) && ((((rowb + j) ^ col) & 2047) != 0);
            }
        }
    }
#pragma unroll
    for (int o = 32; o > 0; o >>= 1) vio += __shfl_xor(vio, o, 64);
    if (lane == 0 && vio > 0) atomicAdd(&g_viol, (unsigned int)vio);
}

// ---------- per-row top-k logsumexp: one wave per row, ballot-popcount bisection ----------
__global__ __launch_bounds__(256) void lse_kernel() {
    const int row_id = (int)((blockIdx.x * blockDim.x + threadIdx.x) >> 6);
    const int lane = threadIdx.x & 63;
    const _Float16* row = g_simh + (size_t)row_id * Nq;
    const int labi = row_id & 2047;
    const float invT = 1.0f / TEMPq;

    long long total = (long long)Nq * 4094LL - (long long)g_viol;
    int k = (int)(total / 8192LL);
    if (k < 1) k = 1;

    float v[64];
    float mx = -1e30f, mn = 1e30f;
    int cnt = 0;
#pragma unroll
    for (int q = 0; q < 8; ++q) {
        int j0 = q * 512 + lane * 8;
        f16x8 x8 = *(const f16x8*)(row + j0);
#pragma unroll
        for (int s = 0; s < 8; ++s) {
            int jj = q * 8 + s;
            int j  = j0 + s;
            float xv = (float)x8[s];
            bool sf = (xv <= 0.9f) && (((j ^ labi) & 2047) != 0);
            float val = sf ? xv : -2.0f;
            v[jj] = val;
            mx = fmaxf(mx, val);
            mn = fminf(mn, sf ? xv : 2.0f);
            cnt += (int)__popcll(__ballot(sf));
        }
    }
#pragma unroll
    for (int o = 32; o > 0; o >>= 1) {
        mx = fmaxf(mx, __shfl_xor(mx, o, 64));
        mn = fminf(mn, __shfl_xor(mn, o, 64));
    }

    const float pos = (float)row[(row_id + Bq) & (Nq - 1)];
    const float mxs = (cnt > 0) ? mx : -10.0f;
    const float ml  = fmaxf(pos, mxs) * invT;

    float lo = mn - 1e-3f, hi = mx;
    int c_hi = 0;
    const bool need = (cnt > k);
    if (need) {
        for (int it = 0; it < 12; ++it) {
            float mid = 0.5f * (lo + hi);
            int c = 0;
#pragma unroll
            for (int jj = 0; jj < 64; ++jj)
                c += (int)__popcll(__ballot(v[jj] > mid));
            if (c > k) lo = mid; else { hi = mid; c_hi = c; }
        }
    }

    float shi = 0.f, st = 0.f; int nt = 0;
#pragma unroll
    for (int jj = 0; jj < 64; ++jj) {
        float x = v[jj];
        float ev = __expf(x * invT - ml);
        if (!need)       { if (x > -1.5f) shi += ev; }
        else if (x > hi) { shi += ev; }
        else if (x > lo) { st += ev; nt++; }
    }
#pragma unroll
    for (int o = 32; o > 0; o >>= 1) {
        shi += __shfl_xor(shi, o, 64);
        st  += __shfl_xor(st,  o, 64);
        nt  += __shfl_xor(nt,  o, 64);
    }
    if (lane == 0) {
        float S = __expf(pos * invT - ml) + shi;
        if (need && c_hi < k && nt > 0)
            S += st * (float)(k - c_hi) / (float)nt;
        g_rowloss[row_id] = (logf(S) + ml) - pos * invT;
    }
}

// ---------- final mean ----------
__global__ __launch_bounds__(256) void loss_kernel(float* __restrict__ out) {
    float s = 0.f;
    for (int i = threadIdx.x; i < Nq; i += 256) s += g_rowloss[i];
    __shared__ float sm[256];
    sm[threadIdx.x] = s; __syncthreads();
    for (int o = 128; o > 0; o >>= 1) {
        if (threadIdx.x < o) sm[threadIdx.x] += sm[threadIdx.x + o];
        __syncthreads();
    }
    if (threadIdx.x == 0) out[0] = sm[0] / (float)Nq;
}

extern "C" void kernel_launch(void* const* d_in, const int* in_sizes, int n_in,
                              void* d_out, int out_size, void* d_ws, size_t ws_size,
                              hipStream_t stream) {
    const float* z         = (const float*)d_in[0];
    const float* query     = (const float*)d_in[3];
    const float* attn_temp = (const float*)d_in[4];
    const float* W         = (const float*)d_in[5];
    const float* bias      = (const float*)d_in[6];
    float* out = (float*)d_out;

    prep_kernel<<<1024 + (Dq * Dq / 4) / 256, 256, 0, stream>>>(z, query, attn_temp, W);
    fw_mfma_kernel<<<dim3(Dq / 128, Nq / 64), 256, 0, stream>>>(bias);
    normalize_kernel<<<Nq / 16, 256, 0, stream>>>();
    sim_mfma_kernel<<<dim3(16, 16), 512, 131072, stream>>>();
    lse_kernel<<<Nq / 4, 256, 0, stream>>>();
    loss_kernel<<<1, 256, 0, stream>>>(out);
}

// Round 16
// 109.477 us; speedup vs baseline: 6.2851x; 1.0278x over previous
//
#include <hip/hip_runtime.h>
#include <hip/hip_bf16.h>
#include <math.h>

#define Bq   2048
#define Cq   8
#define Dq   768
#define NROW 16384      // B*C per half
#define NTOT 32768      // 2*B*C
#define Nq   4096       // 2*B rows of f
#define TEMPq 0.07f
#define NKC  96         // 768/8 k-chunks of 8 bf16 (16 B)

typedef __attribute__((ext_vector_type(8))) short bf16x8;
typedef __attribute__((ext_vector_type(4))) float f32x4;
typedef __attribute__((ext_vector_type(8))) _Float16 f16x8;

// persistent device scratch (fully overwritten every call -> deterministic)
__device__ __hip_bfloat16 g_pooledb[(size_t)Nq * Dq];
__device__ __hip_bfloat16 g_Wb[(size_t)Dq * Dq];
__device__ unsigned short g_fb[(size_t)Nq * Dq];         // f in bf16 (raw bits)
__device__ short          g_fbt[(size_t)NKC * Nq * 8];   // [kc][row][8 bf16] chunk-transposed
__device__ _Float16       g_simh[(size_t)Nq * Nq];
__device__ unsigned int   g_viol;

#define GLDS16(src, dst) __builtin_amdgcn_global_load_lds( \
    (const __attribute__((address_space(1))) void*)(src),  \
    (__attribute__((address_space(3))) void*)(dst), 16, 0, 0)

// ---------- merged: [blocks 0..1023] fused pool, [1024..1599] W->bf16 + init ----------
__global__ __launch_bounds__(256) void prep_kernel(const float* __restrict__ z,
                                                   const float* __restrict__ query,
                                                   const float* __restrict__ attn_temp,
                                                   const float* __restrict__ W,
                                                   float* __restrict__ out) {
    if (blockIdx.x >= 1024) {
        int i = (blockIdx.x - 1024) * 256 + threadIdx.x;
        if (i == 0) { g_viol = 0u; out[0] = 0.f; }   // out accumulated by lse atomics
        float4 v = ((const float4*)W)[i];
        short4 o;
        o.x = ((__hip_bfloat16_raw)__float2bfloat16(v.x)).x;
        o.y = ((__hip_bfloat16_raw)__float2bfloat16(v.y)).x;
        o.z = ((__hip_bfloat16_raw)__float2bfloat16(v.z)).x;
        o.w = ((__hip_bfloat16_raw)__float2bfloat16(v.w)).x;
        ((short4*)g_Wb)[i] = o;
        return;
    }
    int seg  = (int)((blockIdx.x * blockDim.x + threadIdx.x) >> 6);
    int lane = threadIdx.x & 63;
    if (seg >= Nq) return;
    int half = seg >> 11;
    int b    = seg & 2047;
    int baseRow = half * NROW + b * Cq;
    float invt = 1.f / attn_temp[0];

    float4 q4[3];
#pragma unroll
    for (int j = 0; j < 3; ++j) q4[j] = *(const float4*)(query + j * 256 + lane * 4);

    float4 v4[Cq][3];
    float s[Cq];
#pragma unroll
    for (int c = 0; c < Cq; ++c) {
        const float* zr = z + (size_t)(baseRow + c) * Dq;
        float acc = 0.f;
#pragma unroll
        for (int j = 0; j < 3; ++j) {
            float4 vz = *(const float4*)(zr + j * 256 + lane * 4);
            v4[c][j] = vz;
            acc += vz.x * q4[j].x + vz.y * q4[j].y + vz.z * q4[j].z + vz.w * q4[j].w;
        }
#pragma unroll
        for (int o = 32; o > 0; o >>= 1) acc += __shfl_xor(acc, o, 64);
        s[c] = acc * invt;
    }
    float m = s[0];
#pragma unroll
    for (int c = 1; c < Cq; ++c) m = fmaxf(m, s[c]);
    float e[Cq], denom = 0.f;
#pragma unroll
    for (int c = 0; c < Cq; ++c) { e[c] = expf(s[c] - m); denom += e[c]; }
    float inv = 1.f / (denom + 1e-8f);
#pragma unroll
    for (int j = 0; j < 3; ++j) {
        float4 acc = {0.f, 0.f, 0.f, 0.f};
#pragma unroll
        for (int c = 0; c < Cq; ++c) {
            acc.x += v4[c][j].x * e[c];
            acc.y += v4[c][j].y * e[c];
            acc.z += v4[c][j].z * e[c];
            acc.w += v4[c][j].w * e[c];
        }
        short4 o;
        o.x = ((__hip_bfloat16_raw)__float2bfloat16(acc.x * inv)).x;
        o.y = ((__hip_bfloat16_raw)__float2bfloat16(acc.y * inv)).x;
        o.z = ((__hip_bfloat16_raw)__float2bfloat16(acc.z * inv)).x;
        o.w = ((__hip_bfloat16_raw)__float2bfloat16(acc.w * inv)).x;
        *(short4*)((short*)g_pooledb + (size_t)seg * Dq + j * 256 + lane * 4) = o;
    }
}

// ---------- f = pooled @ W^T + b via bf16 MFMA, 64x128 tile; store f as bf16 ----------
__global__ __launch_bounds__(256) void fw_mfma_kernel(const float* __restrict__ bias) {
    __shared__ short lA[64 * 32];     // 4 KB
    __shared__ short lB[128 * 32];    // 8 KB
    const int bm = blockIdx.y * 64;
    const int bn = blockIdx.x * 128;

    const int tid  = threadIdx.x;
    const int wave = tid >> 6, lane = tid & 63;
    const int wm = wave >> 1, wn = wave & 1;       // 2x2 wave grid; per-wave C: 32x64

    const short* A  = (const short*)g_pooledb;
    const short* Bt = (const short*)g_Wb;

    const int srow = lane >> 2;
    const int scol = (lane & 3) * 8;
    const int c0 = wave * 2, c1 = wave * 2 + 1;    // B chunks

    f32x4 acc[2][4];
#pragma unroll
    for (int m = 0; m < 2; ++m)
#pragma unroll
        for (int n = 0; n < 4; ++n) acc[m][n] = (f32x4){0.f, 0.f, 0.f, 0.f};

    for (int k0 = 0; k0 < Dq; k0 += 32) {
        GLDS16(A  + (size_t)(bm + wave * 16 + srow) * Dq + k0 + scol, lA + wave * 512);
        GLDS16(Bt + (size_t)(bn + c0 * 16 + srow) * Dq + k0 + scol, lB + c0 * 512);
        GLDS16(Bt + (size_t)(bn + c1 * 16 + srow) * Dq + k0 + scol, lB + c1 * 512);
        __syncthreads();

        bf16x8 af[2], bfr[4];
#pragma unroll
        for (int m = 0; m < 2; ++m) {
            int row = wm * 32 + m * 16 + (lane & 15);
            af[m] = *(const bf16x8*)(lA + row * 32 + (lane >> 4) * 8);
        }
#pragma unroll
        for (int n = 0; n < 4; ++n) {
            int row = wn * 64 + n * 16 + (lane & 15);
            bfr[n] = *(const bf16x8*)(lB + row * 32 + (lane >> 4) * 8);
        }
#pragma unroll
        for (int m = 0; m < 2; ++m)
#pragma unroll
            for (int n = 0; n < 4; ++n)
                acc[m][n] = __builtin_amdgcn_mfma_f32_16x16x32_bf16(af[m], bfr[n], acc[m][n], 0, 0, 0);
        __syncthreads();
    }

#pragma unroll
    for (int m = 0; m < 2; ++m) {
        int rowb = bm + wm * 32 + m * 16 + (lane >> 4) * 4;
#pragma unroll
        for (int n = 0; n < 4; ++n) {
            int col = bn + wn * 64 + n * 16 + (lane & 15);
            float bc = bias[col];
#pragma unroll
            for (int j = 0; j < 4; ++j)
                g_fb[(size_t)(rowb + j) * Dq + col] =
                    ((__hip_bfloat16_raw)__float2bfloat16(acc[m][n][j] + bc)).x;
        }
    }
}

// ---------- row-normalize (bf16 in, fp32 norm) -> chunk-transposed bf16. 16 rows/block ----------
__global__ __launch_bounds__(256) void normalize_kernel() {
    __shared__ short rowbuf[16][776];
    const int tid = threadIdx.x;
    const int wave = tid >> 6, lane = tid & 63;
    const int r0 = blockIdx.x * 16;

    for (int rr = wave; rr < 16; rr += 4) {
        int row = r0 + rr;
        const unsigned short* fr = g_fb + (size_t)row * Dq;
        float v[12];
        float ss = 0.f;
#pragma unroll
        for (int j = 0; j < 6; ++j) {
            // lane covers 2 consecutive cols -> 4-B loads, coalesced 256 B/16 lanes
            ushort2 u2 = *(const ushort2*)(fr + j * 128 + lane * 2);
            float f0 = __bfloat162float(*(__hip_bfloat16*)&u2.x);
            float f1 = __bfloat162float(*(__hip_bfloat16*)&u2.y);
            v[j * 2]     = f0;
            v[j * 2 + 1] = f1;
            ss += f0 * f0 + f1 * f1;
        }
#pragma unroll
        for (int o = 32; o > 0; o >>= 1) ss += __shfl_xor(ss, o, 64);
        float rn = 1.f / sqrtf(ss);
#pragma unroll
        for (int j = 0; j < 6; ++j) {
            rowbuf[rr][j * 128 + lane * 2]     = ((__hip_bfloat16_raw)__float2bfloat16(v[j * 2] * rn)).x;
            rowbuf[rr][j * 128 + lane * 2 + 1] = ((__hip_bfloat16_raw)__float2bfloat16(v[j * 2 + 1] * rn)).x;
        }
    }
    __syncthreads();
#pragma unroll
    for (int i = 0; i < 6; ++i) {
        int idx = i * 256 + tid;
        int ch = idx >> 4;
        int r  = idx & 15;
        bf16x8 val = *(const bf16x8*)&rowbuf[r][ch * 8];
        *(bf16x8*)&g_fbt[((size_t)ch * Nq + r0 + r) * 8] = val;
    }
}

// ---------- sim = fb @ fb^T : 256^2 tile, 8 waves, BK=64, dbuf + counted vmcnt ----------
#define STAGE_SIM(b, kt_) do {                                                          \
    _Pragma("unroll")                                                                   \
    for (int i = 0; i < 4; ++i) {                                                       \
        GLDS16(fbt + ((size_t)((kt_) * 8 + wave) * Nq + bm + i * 64 + lane) * 8,        \
               As + ((b) * 2048 + wave * 256 + i * 64) * 8);                            \
        GLDS16(fbt + ((size_t)((kt_) * 8 + wave) * Nq + bn + i * 64 + lane) * 8,        \
               Bs + ((b) * 2048 + wave * 256 + i * 64) * 8);                            \
    }                                                                                   \
} while (0)

__global__ __launch_bounds__(512) void sim_mfma_kernel() {
    extern __shared__ short smem[];          // 128 KiB
    short* As = smem;
    short* Bs = smem + 32768;

    const int tid  = threadIdx.x;
    const int wave = tid >> 6, lane = tid & 63;
    const int wm = wave >> 2, wn = wave & 3;
    const int bm = blockIdx.y * 256, bn = blockIdx.x * 256;
    const short* fbt = g_fbt;

    f32x4 acc[8][4];
#pragma unroll
    for (int mi = 0; mi < 8; ++mi)
#pragma unroll
        for (int ni = 0; ni < 4; ++ni) acc[mi][ni] = (f32x4){0.f, 0.f, 0.f, 0.f};

    STAGE_SIM(0, 0);

#pragma unroll 1
    for (int kt = 0; kt < 12; ++kt) {
        const int cur = kt & 1;
        if (kt < 11) {
            STAGE_SIM(cur ^ 1, kt + 1);
            asm volatile("s_waitcnt vmcnt(8)" ::: "memory");
        } else {
            asm volatile("s_waitcnt vmcnt(0)" ::: "memory");
        }
        __builtin_amdgcn_s_barrier();
        __builtin_amdgcn_sched_barrier(0);

#pragma unroll
        for (int ks = 0; ks < 2; ++ks) {
            bf16x8 af[8], bfr[4];
            const int kc = (ks * 4 + (lane >> 4)) * 256;
#pragma unroll
            for (int mi = 0; mi < 8; ++mi)
                af[mi] = *(const bf16x8*)(As + (cur * 2048 + kc + wm * 128 + mi * 16 + (lane & 15)) * 8);
#pragma unroll
            for (int ni = 0; ni < 4; ++ni)
                bfr[ni] = *(const bf16x8*)(Bs + (cur * 2048 + kc + wn * 64 + ni * 16 + (lane & 15)) * 8);
            __builtin_amdgcn_s_setprio(1);
#pragma unroll
            for (int mi = 0; mi < 8; ++mi)
#pragma unroll
                for (int ni = 0; ni < 4; ++ni)
                    acc[mi][ni] = __builtin_amdgcn_mfma_f32_16x16x32_bf16(af[mi], bfr[ni], acc[mi][ni], 0, 0, 0);
            __builtin_amdgcn_s_setprio(0);
        }
        __builtin_amdgcn_sched_barrier(0);
        __builtin_amdgcn_s_barrier();
    }

    // epilogue: fp16 store (full matrix, no mirror) + violation count
    int vio = 0;
#pragma unroll
    for (int mi = 0; mi < 8; ++mi) {
        int rowb = bm + wm * 128 + mi * 16 + (lane >> 4) * 4;
#pragma unroll
        for (int ni = 0; ni < 4; ++ni) {
            int col = bn + wn * 64 + ni * 16 + (lane & 15);
#pragma unroll
            for (int j = 0; j < 4; ++j) {
                float x = acc[mi][ni][j];
                g_simh[(size_t)(rowb + j) * Nq + col] = (_Float16)x;
                vio += (x > 0.9f) && ((((rowb + j) ^ col) & 2047) != 0);
            }
        }
    }
#pragma unroll
    for (int o = 32; o > 0; o >>= 1) vio += __shfl_xor(vio, o, 64);
    if (lane == 0 && vio > 0) atomicAdd(&g_viol, (unsigned int)vio);
}

// ---------- per-row top-k logsumexp + fused mean (1 atomicAdd per block) ----------
__global__ __launch_bounds__(256) void lse_kernel(float* __restrict__ out) {
    const int tid = threadIdx.x;
    const int wave = tid >> 6, lane = tid & 63;
    const int row_id = blockIdx.x * 4 + wave;
    const _Float16* row = g_simh + (size_t)row_id * Nq;
    const int labi = row_id & 2047;
    const float invT = 1.0f / TEMPq;

    long long total = (long long)Nq * 4094LL - (long long)g_viol;
    int k = (int)(total / 8192LL);
    if (k < 1) k = 1;

    float v[64];
    float mx = -1e30f, mn = 1e30f;
    int cnt = 0;
#pragma unroll
    for (int q = 0; q < 8; ++q) {
        int j0 = q * 512 + lane * 8;
        f16x8 x8 = *(const f16x8*)(row + j0);
#pragma unroll
        for (int s = 0; s < 8; ++s) {
            int jj = q * 8 + s;
            int j  = j0 + s;
            float xv = (float)x8[s];
            bool sf = (xv <= 0.9f) && (((j ^ labi) & 2047) != 0);
            float val = sf ? xv : -2.0f;
            v[jj] = val;
            mx = fmaxf(mx, val);
            mn = fminf(mn, sf ? xv : 2.0f);
            cnt += (int)__popcll(__ballot(sf));
        }
    }
#pragma unroll
    for (int o = 32; o > 0; o >>= 1) {
        mx = fmaxf(mx, __shfl_xor(mx, o, 64));
        mn = fminf(mn, __shfl_xor(mn, o, 64));
    }

    const float pos = (float)row[(row_id + Bq) & (Nq - 1)];
    const float mxs = (cnt > 0) ? mx : -10.0f;
    const float ml  = fmaxf(pos, mxs) * invT;

    float lo = mn - 1e-3f, hi = mx;
    int c_hi = 0;
    const bool need = (cnt > k);
    if (need) {
        for (int it = 0; it < 12; ++it) {
            float mid = 0.5f * (lo + hi);
            int c = 0;
#pragma unroll
            for (int jj = 0; jj < 64; ++jj)
                c += (int)__popcll(__ballot(v[jj] > mid));
            if (c > k) lo = mid; else { hi = mid; c_hi = c; }
        }
    }

    float shi = 0.f, st = 0.f; int nt = 0;
#pragma unroll
    for (int jj = 0; jj < 64; ++jj) {
        float x = v[jj];
        float ev = __expf(x * invT - ml);
        if (!need)       { if (x > -1.5f) shi += ev; }
        else if (x > hi) { shi += ev; }
        else if (x > lo) { st += ev; nt++; }
    }
#pragma unroll
    for (int o = 32; o > 0; o >>= 1) {
        shi += __shfl_xor(shi, o, 64);
        st  += __shfl_xor(st,  o, 64);
        nt  += __shfl_xor(nt,  o, 64);
    }
    __shared__ float sblk[4];
    if (lane == 0) {
        float S = __expf(pos * invT - ml) + shi;
        if (need && c_hi < k && nt > 0)
            S += st * (float)(k - c_hi) / (float)nt;
        sblk[wave] = (logf(S) + ml) - pos * invT;
    }
    __syncthreads();
    if (tid == 0) {
        float bs = (sblk[0] + sblk[1] + sblk[2] + sblk[3]) * (1.0f / (float)Nq);
        atomicAdd(out, bs);
    }
}

extern "C" void kernel_launch(void* const* d_in, const int* in_sizes, int n_in,
                              void* d_out, int out_size, void* d_ws, size_t ws_size,
                              hipStream_t stream) {
    const float* z         = (const float*)d_in[0];
    const float* query     = (const float*)d_in[3];
    const float* attn_temp = (const float*)d_in[4];
    const float* W         = (const float*)d_in[5];
    const float* bias      = (const float*)d_in[6];
    float* out = (float*)d_out;

    prep_kernel<<<1024 + (Dq * Dq / 4) / 256, 256, 0, stream>>>(z, query, attn_temp, W, out);
    fw_mfma_kernel<<<dim3(Dq / 128, Nq / 64), 256, 0, stream>>>(bias);
    normalize_kernel<<<Nq / 16, 256, 0, stream>>>();
    sim_mfma_kernel<<<dim3(16, 16), 512, 131072, stream>>>();
    lse_kernel<<<Nq / 4, 256, 0, stream>>>(out);
}

// Round 17
// 106.341 us; speedup vs baseline: 6.4705x; 1.0295x over previous
//
#include <hip/hip_runtime.h>
#include <hip/hip_bf16.h>
#include <math.h>

#define Bq   2048
#define Cq   8
#define Dq   768
#define NROW 16384      // B*C per half
#define NTOT 32768      // 2*B*C
#define Nq   4096       // 2*B rows of f
#define TEMPq 0.07f
#define NKC  96         // 768/8 k-chunks of 8 bf16 (16 B)

typedef __attribute__((ext_vector_type(8))) short bf16x8;
typedef __attribute__((ext_vector_type(4))) float f32x4;
typedef __attribute__((ext_vector_type(8))) _Float16 f16x8;

// persistent device scratch (fully overwritten every call -> deterministic)
__device__ __hip_bfloat16 g_pooledb[(size_t)Nq * Dq];
__device__ __hip_bfloat16 g_Wb[(size_t)Dq * Dq];
__device__ short          g_fbt[(size_t)NKC * Nq * 8];   // UNnormalized f, chunk-transposed
__device__ float          g_ssum[Nq];                    // per-row sum of squares of f
__device__ _Float16       g_simh[(size_t)Nq * Nq];
__device__ unsigned int   g_viol;

#define GLDS16(src, dst) __builtin_amdgcn_global_load_lds( \
    (const __attribute__((address_space(1))) void*)(src),  \
    (__attribute__((address_space(3))) void*)(dst), 16, 0, 0)

// ---------- merged: [blocks 0..1023] fused pool, [1024..1599] W->bf16 + init ----------
__global__ __launch_bounds__(256) void prep_kernel(const float* __restrict__ z,
                                                   const float* __restrict__ query,
                                                   const float* __restrict__ attn_temp,
                                                   const float* __restrict__ W,
                                                   float* __restrict__ out) {
    if (blockIdx.x >= 1024) {
        int i = (blockIdx.x - 1024) * 256 + threadIdx.x;
        if (i == 0) { g_viol = 0u; out[0] = 0.f; }
        if (blockIdx.x == 1024) {
#pragma unroll
            for (int q = 0; q < 16; ++q) g_ssum[threadIdx.x * 16 + q] = 0.f;
        }
        float4 v = ((const float4*)W)[i];
        short4 o;
        o.x = ((__hip_bfloat16_raw)__float2bfloat16(v.x)).x;
        o.y = ((__hip_bfloat16_raw)__float2bfloat16(v.y)).x;
        o.z = ((__hip_bfloat16_raw)__float2bfloat16(v.z)).x;
        o.w = ((__hip_bfloat16_raw)__float2bfloat16(v.w)).x;
        ((short4*)g_Wb)[i] = o;
        return;
    }
    int seg  = (int)((blockIdx.x * blockDim.x + threadIdx.x) >> 6);
    int lane = threadIdx.x & 63;
    if (seg >= Nq) return;
    int half = seg >> 11;
    int b    = seg & 2047;
    int baseRow = half * NROW + b * Cq;
    float invt = 1.f / attn_temp[0];

    float4 q4[3];
#pragma unroll
    for (int j = 0; j < 3; ++j) q4[j] = *(const float4*)(query + j * 256 + lane * 4);

    float4 v4[Cq][3];
    float s[Cq];
#pragma unroll
    for (int c = 0; c < Cq; ++c) {
        const float* zr = z + (size_t)(baseRow + c) * Dq;
        float acc = 0.f;
#pragma unroll
        for (int j = 0; j < 3; ++j) {
            float4 vz = *(const float4*)(zr + j * 256 + lane * 4);
            v4[c][j] = vz;
            acc += vz.x * q4[j].x + vz.y * q4[j].y + vz.z * q4[j].z + vz.w * q4[j].w;
        }
#pragma unroll
        for (int o = 32; o > 0; o >>= 1) acc += __shfl_xor(acc, o, 64);
        s[c] = acc * invt;
    }
    float m = s[0];
#pragma unroll
    for (int c = 1; c < Cq; ++c) m = fmaxf(m, s[c]);
    float e[Cq], denom = 0.f;
#pragma unroll
    for (int c = 0; c < Cq; ++c) { e[c] = expf(s[c] - m); denom += e[c]; }
    float inv = 1.f / (denom + 1e-8f);
#pragma unroll
    for (int j = 0; j < 3; ++j) {
        float4 acc = {0.f, 0.f, 0.f, 0.f};
#pragma unroll
        for (int c = 0; c < Cq; ++c) {
            acc.x += v4[c][j].x * e[c];
            acc.y += v4[c][j].y * e[c];
            acc.z += v4[c][j].z * e[c];
            acc.w += v4[c][j].w * e[c];
        }
        short4 o;
        o.x = ((__hip_bfloat16_raw)__float2bfloat16(acc.x * inv)).x;
        o.y = ((__hip_bfloat16_raw)__float2bfloat16(acc.y * inv)).x;
        o.z = ((__hip_bfloat16_raw)__float2bfloat16(acc.z * inv)).x;
        o.w = ((__hip_bfloat16_raw)__float2bfloat16(acc.w * inv)).x;
        *(short4*)((short*)g_pooledb + (size_t)seg * Dq + j * 256 + lane * 4) = o;
    }
}

// ---------- f = pooled @ W^T + b (UNnormalized) -> chunk-transposed fbt + row ssum ----------
__global__ __launch_bounds__(256) void fw_mfma_kernel(const float* __restrict__ bias) {
    __shared__ short lA[64 * 32];     // 4 KB
    __shared__ short lB[128 * 32];    // 8 KB
    __shared__ short ct[64][136];     // 17.4 KB; stride 136 shorts = 17 x 16B (b128-aligned)
    const int bm = blockIdx.y * 64;
    const int bn = blockIdx.x * 128;

    const int tid  = threadIdx.x;
    const int wave = tid >> 6, lane = tid & 63;
    const int wm = wave >> 1, wn = wave & 1;       // 2x2 wave grid; per-wave C: 32x64

    const short* A  = (const short*)g_pooledb;
    const short* Bt = (const short*)g_Wb;

    const int srow = lane >> 2;
    const int scol = (lane & 3) * 8;
    const int c0 = wave * 2, c1 = wave * 2 + 1;    // B chunks

    f32x4 acc[2][4];
#pragma unroll
    for (int m = 0; m < 2; ++m)
#pragma unroll
        for (int n = 0; n < 4; ++n) acc[m][n] = (f32x4){0.f, 0.f, 0.f, 0.f};

    for (int k0 = 0; k0 < Dq; k0 += 32) {
        GLDS16(A  + (size_t)(bm + wave * 16 + srow) * Dq + k0 + scol, lA + wave * 512);
        GLDS16(Bt + (size_t)(bn + c0 * 16 + srow) * Dq + k0 + scol, lB + c0 * 512);
        GLDS16(Bt + (size_t)(bn + c1 * 16 + srow) * Dq + k0 + scol, lB + c1 * 512);
        __syncthreads();

        bf16x8 af[2], bfr[4];
#pragma unroll
        for (int m = 0; m < 2; ++m) {
            int row = wm * 32 + m * 16 + (lane & 15);
            af[m] = *(const bf16x8*)(lA + row * 32 + (lane >> 4) * 8);
        }
#pragma unroll
        for (int n = 0; n < 4; ++n) {
            int row = wn * 64 + n * 16 + (lane & 15);
            bfr[n] = *(const bf16x8*)(lB + row * 32 + (lane >> 4) * 8);
        }
#pragma unroll
        for (int m = 0; m < 2; ++m)
#pragma unroll
            for (int n = 0; n < 4; ++n)
                acc[m][n] = __builtin_amdgcn_mfma_f32_16x16x32_bf16(af[m], bfr[n], acc[m][n], 0, 0, 0);
        __syncthreads();
    }

    // epilogue: bias-add -> LDS tile (bf16) + per-row sum-of-squares partials
    float ssp[2][4];
#pragma unroll
    for (int m = 0; m < 2; ++m)
#pragma unroll
        for (int j = 0; j < 4; ++j) ssp[m][j] = 0.f;
#pragma unroll
    for (int m = 0; m < 2; ++m) {
        int rloc = wm * 32 + m * 16 + (lane >> 4) * 4;
#pragma unroll
        for (int n = 0; n < 4; ++n) {
            int cloc = wn * 64 + n * 16 + (lane & 15);
            float bc = bias[bn + cloc];
#pragma unroll
            for (int j = 0; j < 4; ++j) {
                float x = acc[m][n][j] + bc;
                ct[rloc + j][cloc] = ((__hip_bfloat16_raw)__float2bfloat16(x)).x;
                ssp[m][j] += x * x;
            }
        }
    }
    // reduce over the 16 lanes sharing each row (lane&15 varies cols)
#pragma unroll
    for (int m = 0; m < 2; ++m)
#pragma unroll
        for (int j = 0; j < 4; ++j) {
#pragma unroll
            for (int o = 1; o < 16; o <<= 1) ssp[m][j] += __shfl_xor(ssp[m][j], o, 64);
        }
    if ((lane & 15) == 0) {
        int rbase = bm + wm * 32 + (lane >> 4) * 4;
#pragma unroll
        for (int m = 0; m < 2; ++m)
#pragma unroll
            for (int j = 0; j < 4; ++j)
                atomicAdd(&g_ssum[rbase + m * 16 + j], ssp[m][j]);
    }
    __syncthreads();

    // chunk-transposed write: idx -> (row 0..63, chunk 0..15); 16B per thread-iter
#pragma unroll
    for (int i = 0; i < 4; ++i) {
        int idx = i * 256 + tid;
        int r   = idx & 63;
        int chl = idx >> 6;               // 0..15
        bf16x8 val = *(const bf16x8*)&ct[r][chl * 8];
        *(bf16x8*)&g_fbt[((size_t)(bn / 8 + chl) * Nq + bm + r) * 8] = val;
    }
}

// ---------- sim = fb @ fb^T : 256^2 tile, 8 waves, BK=64, dbuf + counted vmcnt ----------
// epilogue applies rsqrt(ssum_i)*rsqrt(ssum_j) (normalization commutes with the dot)
#define STAGE_SIM(b, kt_) do {                                                          \
    _Pragma("unroll")                                                                   \
    for (int i = 0; i < 4; ++i) {                                                       \
        GLDS16(fbt + ((size_t)((kt_) * 8 + wave) * Nq + bm + i * 64 + lane) * 8,        \
               As + ((b) * 2048 + wave * 256 + i * 64) * 8);                            \
        GLDS16(fbt + ((size_t)((kt_) * 8 + wave) * Nq + bn + i * 64 + lane) * 8,        \
               Bs + ((b) * 2048 + wave * 256 + i * 64) * 8);                            \
    }                                                                                   \
} while (0)

__global__ __launch_bounds__(512) void sim_mfma_kernel() {
    extern __shared__ short smem[];          // 128 KiB
    short* As = smem;
    short* Bs = smem + 32768;

    const int tid  = threadIdx.x;
    const int wave = tid >> 6, lane = tid & 63;
    const int wm = wave >> 2, wn = wave & 3;
    const int bm = blockIdx.y * 256, bn = blockIdx.x * 256;
    const short* fbt = g_fbt;

    f32x4 acc[8][4];
#pragma unroll
    for (int mi = 0; mi < 8; ++mi)
#pragma unroll
        for (int ni = 0; ni < 4; ++ni) acc[mi][ni] = (f32x4){0.f, 0.f, 0.f, 0.f};

    STAGE_SIM(0, 0);

#pragma unroll 1
    for (int kt = 0; kt < 12; ++kt) {
        const int cur = kt & 1;
        if (kt < 11) {
            STAGE_SIM(cur ^ 1, kt + 1);
            asm volatile("s_waitcnt vmcnt(8)" ::: "memory");
        } else {
            asm volatile("s_waitcnt vmcnt(0)" ::: "memory");
        }
        __builtin_amdgcn_s_barrier();
        __builtin_amdgcn_sched_barrier(0);

#pragma unroll
        for (int ks = 0; ks < 2; ++ks) {
            bf16x8 af[8], bfr[4];
            const int kc = (ks * 4 + (lane >> 4)) * 256;
#pragma unroll
            for (int mi = 0; mi < 8; ++mi)
                af[mi] = *(const bf16x8*)(As + (cur * 2048 + kc + wm * 128 + mi * 16 + (lane & 15)) * 8);
#pragma unroll
            for (int ni = 0; ni < 4; ++ni)
                bfr[ni] = *(const bf16x8*)(Bs + (cur * 2048 + kc + wn * 64 + ni * 16 + (lane & 15)) * 8);
            __builtin_amdgcn_s_setprio(1);
#pragma unroll
            for (int mi = 0; mi < 8; ++mi)
#pragma unroll
                for (int ni = 0; ni < 4; ++ni)
                    acc[mi][ni] = __builtin_amdgcn_mfma_f32_16x16x32_bf16(af[mi], bfr[ni], acc[mi][ni], 0, 0, 0);
            __builtin_amdgcn_s_setprio(0);
        }
        __builtin_amdgcn_sched_barrier(0);
        __builtin_amdgcn_s_barrier();
    }

    // epilogue: normalize, fp16 store, violation count
    float rn_c[4];
#pragma unroll
    for (int ni = 0; ni < 4; ++ni) {
        int col = bn + wn * 64 + ni * 16 + (lane & 15);
        rn_c[ni] = rsqrtf(g_ssum[col]);
    }
    int vio = 0;
#pragma unroll
    for (int mi = 0; mi < 8; ++mi) {
        int rowb = bm + wm * 128 + mi * 16 + (lane >> 4) * 4;
        float rn_r[4];
#pragma unroll
        for (int j = 0; j < 4; ++j) rn_r[j] = rsqrtf(g_ssum[rowb + j]);
#pragma unroll
        for (int ni = 0; ni < 4; ++ni) {
            int col = bn + wn * 64 + ni * 16 + (lane & 15);
#pragma unroll
            for (int j = 0; j < 4; ++j) {
                float x = acc[mi][ni][j] * rn_r[j] * rn_c[ni];
                g_simh[(size_t)(rowb + j) * Nq + col] = (_Float16)x;
                vio += (x > 0.9f) && ((((rowb + j) ^ col) & 2047) != 0);
            }
        }
    }
#pragma unroll
    for (int o = 32; o > 0; o >>= 1) vio += __shfl_xor(vio, o, 64);
    if (lane == 0 && vio > 0) atomicAdd(&g_viol, (unsigned int)vio);
}

// ---------- per-row top-k logsumexp + fused mean (1 atomicAdd per block) ----------
__global__ __launch_bounds__(256) void lse_kernel(float* __restrict__ out) {
    const int tid = threadIdx.x;
    const int wave = tid >> 6, lane = tid & 63;
    const int row_id = blockIdx.x * 4 + wave;
    const _Float16* row = g_simh + (size_t)row_id * Nq;
    const int labi = row_id & 2047;
    const float invT = 1.0f / TEMPq;

    long long total = (long long)Nq * 4094LL - (long long)g_viol;
    int k = (int)(total / 8192LL);
    if (k < 1) k = 1;

    float v[64];
    float mx = -1e30f, mn = 1e30f;
    int cnt = 0;
#pragma unroll
    for (int q = 0; q < 8; ++q) {
        int j0 = q * 512 + lane * 8;
        f16x8 x8 = *(const f16x8*)(row + j0);
#pragma unroll
        for (int s = 0; s < 8; ++s) {
            int jj = q * 8 + s;
            int j  = j0 + s;
            float xv = (float)x8[s];
            bool sf = (xv <= 0.9f) && (((j ^ labi) & 2047) != 0);
            float val = sf ? xv : -2.0f;
            v[jj] = val;
            mx = fmaxf(mx, val);
            mn = fminf(mn, sf ? xv : 2.0f);
            cnt += (int)__popcll(__ballot(sf));
        }
    }
#pragma unroll
    for (int o = 32; o > 0; o >>= 1) {
        mx = fmaxf(mx, __shfl_xor(mx, o, 64));
        mn = fminf(mn, __shfl_xor(mn, o, 64));
    }

    const float pos = (float)row[(row_id + Bq) & (Nq - 1)];
    const float mxs = (cnt > 0) ? mx : -10.0f;
    const float ml  = fmaxf(pos, mxs) * invT;

    float lo = mn - 1e-3f, hi = mx;
    int c_hi = 0;
    const bool need = (cnt > k);
    if (need) {
        for (int it = 0; it < 12; ++it) {
            float mid = 0.5f * (lo + hi);
            int c = 0;
#pragma unroll
            for (int jj = 0; jj < 64; ++jj)
                c += (int)__popcll(__ballot(v[jj] > mid));
            if (c > k) lo = mid; else { hi = mid; c_hi = c; }
        }
    }

    float shi = 0.f, st = 0.f; int nt = 0;
#pragma unroll
    for (int jj = 0; jj < 64; ++jj) {
        float x = v[jj];
        float ev = __expf(x * invT - ml);
        if (!need)       { if (x > -1.5f) shi += ev; }
        else if (x > hi) { shi += ev; }
        else if (x > lo) { st += ev; nt++; }
    }
#pragma unroll
    for (int o = 32; o > 0; o >>= 1) {
        shi += __shfl_xor(shi, o, 64);
        st  += __shfl_xor(st,  o, 64);
        nt  += __shfl_xor(nt,  o, 64);
    }
    __shared__ float sblk[4];
    if (lane == 0) {
        float S = __expf(pos * invT - ml) + shi;
        if (need && c_hi < k && nt > 0)
            S += st * (float)(k - c_hi) / (float)nt;
        sblk[wave] = (logf(S) + ml) - pos * invT;
    }
    __syncthreads();
    if (tid == 0) {
        float bs = (sblk[0] + sblk[1] + sblk[2] + sblk[3]) * (1.0f / (float)Nq);
        atomicAdd(out, bs);
    }
}

extern "C" void kernel_launch(void* const* d_in, const int* in_sizes, int n_in,
                              void* d_out, int out_size, void* d_ws, size_t ws_size,
                              hipStream_t stream) {
    const float* z         = (const float*)d_in[0];
    const float* query     = (const float*)d_in[3];
    const float* attn_temp = (const float*)d_in[4];
    const float* W         = (const float*)d_in[5];
    const float* bias      = (const float*)d_in[6];
    float* out = (float*)d_out;

    prep_kernel<<<1024 + (Dq * Dq / 4) / 256, 256, 0, stream>>>(z, query, attn_temp, W, out);
    fw_mfma_kernel<<<dim3(Dq / 128, Nq / 64), 256, 0, stream>>>(bias);
    sim_mfma_kernel<<<dim3(16, 16), 512, 131072, stream>>>();
    lse_kernel<<<Nq / 4, 256, 0, stream>>>(out);
}

// Round 18
// 104.227 us; speedup vs baseline: 6.6018x; 1.0203x over previous
//
#include <hip/hip_runtime.h>
#include <hip/hip_bf16.h>
#include <math.h>

#define Bq   2048
#define Cq   8
#define Dq   768
#define NROW 16384      // B*C per half
#define NTOT 32768      // 2*B*C
#define Nq   4096       // 2*B rows of f
#define TEMPq 0.07f
#define NKC  96         // 768/8 k-chunks of 8 bf16 (16 B)

typedef __attribute__((ext_vector_type(8))) short bf16x8;
typedef __attribute__((ext_vector_type(4))) float f32x4;
typedef __attribute__((ext_vector_type(16))) float f32x16;
typedef __attribute__((ext_vector_type(8))) _Float16 f16x8;

// persistent device scratch (fully overwritten every call -> deterministic)
__device__ __hip_bfloat16 g_pooledb[(size_t)Nq * Dq];
__device__ __hip_bfloat16 g_Wb[(size_t)Dq * Dq];
__device__ short          g_fbt[(size_t)NKC * Nq * 8];   // UNnormalized f, chunk-transposed
__device__ float          g_ssum[Nq];                    // per-row sum of squares of f
__device__ _Float16       g_simh[(size_t)Nq * Nq];
__device__ unsigned int   g_viol;

#define GLDS16(src, dst) __builtin_amdgcn_global_load_lds( \
    (const __attribute__((address_space(1))) void*)(src),  \
    (__attribute__((address_space(3))) void*)(dst), 16, 0, 0)

// ---------- merged: [blocks 0..1023] fused pool, [1024..1599] W->bf16 + init ----------
__global__ __launch_bounds__(256) void prep_kernel(const float* __restrict__ z,
                                                   const float* __restrict__ query,
                                                   const float* __restrict__ attn_temp,
                                                   const float* __restrict__ W,
                                                   float* __restrict__ out) {
    if (blockIdx.x >= 1024) {
        int i = (blockIdx.x - 1024) * 256 + threadIdx.x;
        if (i == 0) { g_viol = 0u; out[0] = 0.f; }
        if (blockIdx.x == 1024) {
#pragma unroll
            for (int q = 0; q < 16; ++q) g_ssum[threadIdx.x * 16 + q] = 0.f;
        }
        float4 v = ((const float4*)W)[i];
        short4 o;
        o.x = ((__hip_bfloat16_raw)__float2bfloat16(v.x)).x;
        o.y = ((__hip_bfloat16_raw)__float2bfloat16(v.y)).x;
        o.z = ((__hip_bfloat16_raw)__float2bfloat16(v.z)).x;
        o.w = ((__hip_bfloat16_raw)__float2bfloat16(v.w)).x;
        ((short4*)g_Wb)[i] = o;
        return;
    }
    int seg  = (int)((blockIdx.x * blockDim.x + threadIdx.x) >> 6);
    int lane = threadIdx.x & 63;
    if (seg >= Nq) return;
    int half = seg >> 11;
    int b    = seg & 2047;
    int baseRow = half * NROW + b * Cq;
    float invt = 1.f / attn_temp[0];

    float4 q4[3];
#pragma unroll
    for (int j = 0; j < 3; ++j) q4[j] = *(const float4*)(query + j * 256 + lane * 4);

    float4 v4[Cq][3];
    float s[Cq];
#pragma unroll
    for (int c = 0; c < Cq; ++c) {
        const float* zr = z + (size_t)(baseRow + c) * Dq;
        float acc = 0.f;
#pragma unroll
        for (int j = 0; j < 3; ++j) {
            float4 vz = *(const float4*)(zr + j * 256 + lane * 4);
            v4[c][j] = vz;
            acc += vz.x * q4[j].x + vz.y * q4[j].y + vz.z * q4[j].z + vz.w * q4[j].w;
        }
#pragma unroll
        for (int o = 32; o > 0; o >>= 1) acc += __shfl_xor(acc, o, 64);
        s[c] = acc * invt;
    }
    float m = s[0];
#pragma unroll
    for (int c = 1; c < Cq; ++c) m = fmaxf(m, s[c]);
    float e[Cq], denom = 0.f;
#pragma unroll
    for (int c = 0; c < Cq; ++c) { e[c] = expf(s[c] - m); denom += e[c]; }
    float inv = 1.f / (denom + 1e-8f);
#pragma unroll
    for (int j = 0; j < 3; ++j) {
        float4 acc = {0.f, 0.f, 0.f, 0.f};
#pragma unroll
        for (int c = 0; c < Cq; ++c) {
            acc.x += v4[c][j].x * e[c];
            acc.y += v4[c][j].y * e[c];
            acc.z += v4[c][j].z * e[c];
            acc.w += v4[c][j].w * e[c];
        }
        short4 o;
        o.x = ((__hip_bfloat16_raw)__float2bfloat16(acc.x * inv)).x;
        o.y = ((__hip_bfloat16_raw)__float2bfloat16(acc.y * inv)).x;
        o.z = ((__hip_bfloat16_raw)__float2bfloat16(acc.z * inv)).x;
        o.w = ((__hip_bfloat16_raw)__float2bfloat16(acc.w * inv)).x;
        *(short4*)((short*)g_pooledb + (size_t)seg * Dq + j * 256 + lane * 4) = o;
    }
}

// ---------- f = pooled @ W^T + b (UNnormalized) -> chunk-transposed fbt + row ssum ----------
__global__ __launch_bounds__(256) void fw_mfma_kernel(const float* __restrict__ bias) {
    __shared__ short lA[64 * 32];     // 4 KB
    __shared__ short lB[128 * 32];    // 8 KB
    __shared__ short ct[64][136];     // 17.4 KB; stride 136 shorts = 17 x 16B (b128-aligned)
    const int bm = blockIdx.y * 64;
    const int bn = blockIdx.x * 128;

    const int tid  = threadIdx.x;
    const int wave = tid >> 6, lane = tid & 63;
    const int wm = wave >> 1, wn = wave & 1;       // 2x2 wave grid; per-wave C: 32x64

    const short* A  = (const short*)g_pooledb;
    const short* Bt = (const short*)g_Wb;

    const int srow = lane >> 2;
    const int scol = (lane & 3) * 8;
    const int c0 = wave * 2, c1 = wave * 2 + 1;    // B chunks

    f32x4 acc[2][4];
#pragma unroll
    for (int m = 0; m < 2; ++m)
#pragma unroll
        for (int n = 0; n < 4; ++n) acc[m][n] = (f32x4){0.f, 0.f, 0.f, 0.f};

    for (int k0 = 0; k0 < Dq; k0 += 32) {
        GLDS16(A  + (size_t)(bm + wave * 16 + srow) * Dq + k0 + scol, lA + wave * 512);
        GLDS16(Bt + (size_t)(bn + c0 * 16 + srow) * Dq + k0 + scol, lB + c0 * 512);
        GLDS16(Bt + (size_t)(bn + c1 * 16 + srow) * Dq + k0 + scol, lB + c1 * 512);
        __syncthreads();

        bf16x8 af[2], bfr[4];
#pragma unroll
        for (int m = 0; m < 2; ++m) {
            int row = wm * 32 + m * 16 + (lane & 15);
            af[m] = *(const bf16x8*)(lA + row * 32 + (lane >> 4) * 8);
        }
#pragma unroll
        for (int n = 0; n < 4; ++n) {
            int row = wn * 64 + n * 16 + (lane & 15);
            bfr[n] = *(const bf16x8*)(lB + row * 32 + (lane >> 4) * 8);
        }
#pragma unroll
        for (int m = 0; m < 2; ++m)
#pragma unroll
            for (int n = 0; n < 4; ++n)
                acc[m][n] = __builtin_amdgcn_mfma_f32_16x16x32_bf16(af[m], bfr[n], acc[m][n], 0, 0, 0);
        __syncthreads();
    }

    // epilogue: bias-add -> LDS tile (bf16) + per-row sum-of-squares partials
    float ssp[2][4];
#pragma unroll
    for (int m = 0; m < 2; ++m)
#pragma unroll
        for (int j = 0; j < 4; ++j) ssp[m][j] = 0.f;
#pragma unroll
    for (int m = 0; m < 2; ++m) {
        int rloc = wm * 32 + m * 16 + (lane >> 4) * 4;
#pragma unroll
        for (int n = 0; n < 4; ++n) {
            int cloc = wn * 64 + n * 16 + (lane & 15);
            float bc = bias[bn + cloc];
#pragma unroll
            for (int j = 0; j < 4; ++j) {
                float x = acc[m][n][j] + bc;
                ct[rloc + j][cloc] = ((__hip_bfloat16_raw)__float2bfloat16(x)).x;
                ssp[m][j] += x * x;
            }
        }
    }
#pragma unroll
    for (int m = 0; m < 2; ++m)
#pragma unroll
        for (int j = 0; j < 4; ++j) {
#pragma unroll
            for (int o = 1; o < 16; o <<= 1) ssp[m][j] += __shfl_xor(ssp[m][j], o, 64);
        }
    if ((lane & 15) == 0) {
        int rbase = bm + wm * 32 + (lane >> 4) * 4;
#pragma unroll
        for (int m = 0; m < 2; ++m)
#pragma unroll
            for (int j = 0; j < 4; ++j)
                atomicAdd(&g_ssum[rbase + m * 16 + j], ssp[m][j]);
    }
    __syncthreads();

#pragma unroll
    for (int i = 0; i < 4; ++i) {
        int idx = i * 256 + tid;
        int r   = idx & 63;
        int chl = idx >> 6;               // 0..15
        bf16x8 val = *(const bf16x8*)&ct[r][chl * 8];
        *(bf16x8*)&g_fbt[((size_t)(bn / 8 + chl) * Nq + bm + r) * 8] = val;
    }
}

// ---------- sim = fb @ fb^T : 256^2 tile, 8 waves, BK=64, 32x32x16 MFMA, dbuf + counted vmcnt ----------
// epilogue applies rsqrt(ssum_i)*rsqrt(ssum_j) (normalization commutes with the dot)
#define STAGE_SIM(b, kt_) do {                                                          \
    _Pragma("unroll")                                                                   \
    for (int i = 0; i < 4; ++i) {                                                       \
        GLDS16(fbt + ((size_t)((kt_) * 8 + wave) * Nq + bm + i * 64 + lane) * 8,        \
               As + ((b) * 2048 + wave * 256 + i * 64) * 8);                            \
        GLDS16(fbt + ((size_t)((kt_) * 8 + wave) * Nq + bn + i * 64 + lane) * 8,        \
               Bs + ((b) * 2048 + wave * 256 + i * 64) * 8);                            \
    }                                                                                   \
} while (0)

__global__ __launch_bounds__(512) void sim_mfma_kernel() {
    extern __shared__ short smem[];          // 128 KiB
    short* As = smem;
    short* Bs = smem + 32768;

    const int tid  = threadIdx.x;
    const int wave = tid >> 6, lane = tid & 63;
    const int wm = wave >> 2, wn = wave & 3;
    const int bm = blockIdx.y * 256, bn = blockIdx.x * 256;
    const short* fbt = g_fbt;

    // per-wave C tile: 128x64 as 4x2 fragments of 32x32; acc = 16 f32/lane each
    f32x16 acc[4][2];
#pragma unroll
    for (int mi = 0; mi < 4; ++mi)
#pragma unroll
        for (int ni = 0; ni < 2; ++ni)
#pragma unroll
            for (int r = 0; r < 16; ++r) acc[mi][ni][r] = 0.f;

    STAGE_SIM(0, 0);

#pragma unroll 1
    for (int kt = 0; kt < 12; ++kt) {
        const int cur = kt & 1;
        if (kt < 11) {
            STAGE_SIM(cur ^ 1, kt + 1);
            asm volatile("s_waitcnt vmcnt(8)" ::: "memory");
        } else {
            asm volatile("s_waitcnt vmcnt(0)" ::: "memory");
        }
        __builtin_amdgcn_s_barrier();
        __builtin_amdgcn_sched_barrier(0);

        // BK=64 = 4 K-steps of 16; chunk kc = ks*2 + (lane>>5)
#pragma unroll
        for (int ks = 0; ks < 4; ++ks) {
            bf16x8 af[4], bfr[2];
            const int kc = (ks * 2 + (lane >> 5)) * 256;
#pragma unroll
            for (int mi = 0; mi < 4; ++mi)
                af[mi] = *(const bf16x8*)(As + (cur * 2048 + kc + wm * 128 + mi * 32 + (lane & 31)) * 8);
#pragma unroll
            for (int ni = 0; ni < 2; ++ni)
                bfr[ni] = *(const bf16x8*)(Bs + (cur * 2048 + kc + wn * 64 + ni * 32 + (lane & 31)) * 8);
            __builtin_amdgcn_s_setprio(1);
#pragma unroll
            for (int mi = 0; mi < 4; ++mi)
#pragma unroll
                for (int ni = 0; ni < 2; ++ni)
                    acc[mi][ni] = __builtin_amdgcn_mfma_f32_32x32x16_bf16(af[mi], bfr[ni], acc[mi][ni], 0, 0, 0);
            __builtin_amdgcn_s_setprio(0);
        }
        __builtin_amdgcn_sched_barrier(0);
        __builtin_amdgcn_s_barrier();
    }

    // epilogue: normalize, fp16 store, violation count.
    // 32x32 C/D layout: col = lane&31, row = (reg&3) + 8*(reg>>2) + 4*(lane>>5)  [m74/m101]
    float rn_c[2];
#pragma unroll
    for (int ni = 0; ni < 2; ++ni) {
        int col = bn + wn * 64 + ni * 32 + (lane & 31);
        rn_c[ni] = rsqrtf(g_ssum[col]);
    }
    int vio = 0;
#pragma unroll
    for (int mi = 0; mi < 4; ++mi) {
        int rbase = bm + wm * 128 + mi * 32 + 4 * (lane >> 5);
        float rn_r[16];
#pragma unroll
        for (int r = 0; r < 16; ++r)
            rn_r[r] = rsqrtf(g_ssum[rbase + (r & 3) + 8 * (r >> 2)]);
#pragma unroll
        for (int ni = 0; ni < 2; ++ni) {
            int col = bn + wn * 64 + ni * 32 + (lane & 31);
#pragma unroll
            for (int r = 0; r < 16; ++r) {
                int row = rbase + (r & 3) + 8 * (r >> 2);
                float x = acc[mi][ni][r] * rn_r[r] * rn_c[ni];
                g_simh[(size_t)row * Nq + col] = (_Float16)x;
                vio += (x > 0.9f) && (((row ^ col) & 2047) != 0);
            }
        }
    }
#pragma unroll
    for (int o = 32; o > 0; o >>= 1) vio += __shfl_xor(vio, o, 64);
    if (lane == 0 && vio > 0) atomicAdd(&g_viol, (unsigned int)vio);
}

// ---------- per-row top-k logsumexp + fused mean (1 atomicAdd per block) ----------
__global__ __launch_bounds__(256) void lse_kernel(float* __restrict__ out) {
    const int tid = threadIdx.x;
    const int wave = tid >> 6, lane = tid & 63;
    const int row_id = blockIdx.x * 4 + wave;
    const _Float16* row = g_simh + (size_t)row_id * Nq;
    const int labi = row_id & 2047;
    const float invT = 1.0f / TEMPq;

    long long total = (long long)Nq * 4094LL - (long long)g_viol;
    int k = (int)(total / 8192LL);
    if (k < 1) k = 1;

    float v[64];
    float mx = -1e30f, mn = 1e30f;
    int cnt = 0;
#pragma unroll
    for (int q = 0; q < 8; ++q) {
        int j0 = q * 512 + lane * 8;
        f16x8 x8 = *(const f16x8*)(row + j0);
#pragma unroll
        for (int s = 0; s < 8; ++s) {
            int jj = q * 8 + s;
            int j  = j0 + s;
            float xv = (float)x8[s];
            bool sf = (xv <= 0.9f) && (((j ^ labi) & 2047) != 0);
            float val = sf ? xv : -2.0f;
            v[jj] = val;
            mx = fmaxf(mx, val);
            mn = fminf(mn, sf ? xv : 2.0f);
            cnt += (int)__popcll(__ballot(sf));
        }
    }
#pragma unroll
    for (int o = 32; o > 0; o >>= 1) {
        mx = fmaxf(mx, __shfl_xor(mx, o, 64));
        mn = fminf(mn, __shfl_xor(mn, o, 64));
    }

    const float pos = (float)row[(row_id + Bq) & (Nq - 1)];
    const float mxs = (cnt > 0) ? mx : -10.0f;
    const float ml  = fmaxf(pos, mxs) * invT;

    float lo = mn - 1e-3f, hi = mx;
    int c_hi = 0;
    const bool need = (cnt > k);
    if (need) {
        for (int it = 0; it < 9; ++it) {       // final bracket ~6e-4 -> loss err ~1e-3 << 0.166
            float mid = 0.5f * (lo + hi);
            int c = 0;
#pragma unroll
            for (int jj = 0; jj < 64; ++jj)
                c += (int)__popcll(__ballot(v[jj] > mid));
            if (c > k) lo = mid; else { hi = mid; c_hi = c; }
        }
    }

    float shi = 0.f, st = 0.f; int nt = 0;
#pragma unroll
    for (int jj = 0; jj < 64; ++jj) {
        float x = v[jj];
        float ev = __expf(x * invT - ml);
        if (!need)       { if (x > -1.5f) shi += ev; }
        else if (x > hi) { shi += ev; }
        else if (x > lo) { st += ev; nt++; }
    }
#pragma unroll
    for (int o = 32; o > 0; o >>= 1) {
        shi += __shfl_xor(shi, o, 64);
        st  += __shfl_xor(st,  o, 64);
        nt  += __shfl_xor(nt,  o, 64);
    }
    __shared__ float sblk[4];
    if (lane == 0) {
        float S = __expf(pos * invT - ml) + shi;
        if (need && c_hi < k && nt > 0)
            S += st * (float)(k - c_hi) / (float)nt;
        sblk[wave] = (logf(S) + ml) - pos * invT;
    }
    __syncthreads();
    if (tid == 0) {
        float bs = (sblk[0] + sblk[1] + sblk[2] + sblk[3]) * (1.0f / (float)Nq);
        atomicAdd(out, bs);
    }
}

extern "C" void kernel_launch(void* const* d_in, const int* in_sizes, int n_in,
                              void* d_out, int out_size, void* d_ws, size_t ws_size,
                              hipStream_t stream) {
    const float* z         = (const float*)d_in[0];
    const float* query     = (const float*)d_in[3];
    const float* attn_temp = (const float*)d_in[4];
    const float* W         = (const float*)d_in[5];
    const float* bias      = (const float*)d_in[6];
    float* out = (float*)d_out;

    prep_kernel<<<1024 + (Dq * Dq / 4) / 256, 256, 0, stream>>>(z, query, attn_temp, W, out);
    fw_mfma_kernel<<<dim3(Dq / 128, Nq / 64), 256, 0, stream>>>(bias);
    sim_mfma_kernel<<<dim3(16, 16), 512, 131072, stream>>>();
    lse_kernel<<<Nq / 4, 256, 0, stream>>>(out);
}

// Round 19
// 103.634 us; speedup vs baseline: 6.6396x; 1.0057x over previous
//
#include <hip/hip_runtime.h>
#include <hip/hip_bf16.h>
#include <math.h>

#define Bq   2048
#define Cq   8
#define Dq   768
#define NROW 16384      // B*C per half
#define NTOT 32768      // 2*B*C
#define Nq   4096       // 2*B rows of f
#define TEMPq 0.07f
#define NKC  96         // 768/8 k-chunks of 8 bf16 (16 B)

typedef __attribute__((ext_vector_type(8))) short bf16x8;
typedef __attribute__((ext_vector_type(4))) float f32x4;
typedef __attribute__((ext_vector_type(16))) float f32x16;
typedef __attribute__((ext_vector_type(8))) _Float16 f16x8;

// persistent device scratch (fully overwritten every call -> deterministic)
__device__ __hip_bfloat16 g_pooledb[(size_t)Nq * Dq];
__device__ __hip_bfloat16 g_Wb[(size_t)Dq * Dq];
__device__ short          g_fbt[(size_t)NKC * Nq * 8];   // UNnormalized f, chunk-transposed
__device__ float          g_ssum[Nq];                    // per-row sum of squares of f
__device__ _Float16       g_simh[(size_t)Nq * Nq];
__device__ unsigned int   g_viol;

#define GLDS16(src, dst) __builtin_amdgcn_global_load_lds( \
    (const __attribute__((address_space(1))) void*)(src),  \
    (__attribute__((address_space(3))) void*)(dst), 16, 0, 0)

// ---------- merged: [blocks 0..1023] fused pool, [1024..1599] W->bf16 + init ----------
__global__ __launch_bounds__(256) void prep_kernel(const float* __restrict__ z,
                                                   const float* __restrict__ query,
                                                   const float* __restrict__ attn_temp,
                                                   const float* __restrict__ W,
                                                   float* __restrict__ out) {
    if (blockIdx.x >= 1024) {
        int i = (blockIdx.x - 1024) * 256 + threadIdx.x;
        if (i == 0) { g_viol = 0u; out[0] = 0.f; }
        if (blockIdx.x == 1024) {
#pragma unroll
            for (int q = 0; q < 16; ++q) g_ssum[threadIdx.x * 16 + q] = 0.f;
        }
        float4 v = ((const float4*)W)[i];
        short4 o;
        o.x = ((__hip_bfloat16_raw)__float2bfloat16(v.x)).x;
        o.y = ((__hip_bfloat16_raw)__float2bfloat16(v.y)).x;
        o.z = ((__hip_bfloat16_raw)__float2bfloat16(v.z)).x;
        o.w = ((__hip_bfloat16_raw)__float2bfloat16(v.w)).x;
        ((short4*)g_Wb)[i] = o;
        return;
    }
    int seg  = (int)((blockIdx.x * blockDim.x + threadIdx.x) >> 6);
    int lane = threadIdx.x & 63;
    if (seg >= Nq) return;
    int half = seg >> 11;
    int b    = seg & 2047;
    int baseRow = half * NROW + b * Cq;
    float invt = 1.f / attn_temp[0];

    float4 q4[3];
#pragma unroll
    for (int j = 0; j < 3; ++j) q4[j] = *(const float4*)(query + j * 256 + lane * 4);

    float4 v4[Cq][3];
    float s[Cq];
#pragma unroll
    for (int c = 0; c < Cq; ++c) {
        const float* zr = z + (size_t)(baseRow + c) * Dq;
        float acc = 0.f;
#pragma unroll
        for (int j = 0; j < 3; ++j) {
            float4 vz = *(const float4*)(zr + j * 256 + lane * 4);
            v4[c][j] = vz;
            acc += vz.x * q4[j].x + vz.y * q4[j].y + vz.z * q4[j].z + vz.w * q4[j].w;
        }
#pragma unroll
        for (int o = 32; o > 0; o >>= 1) acc += __shfl_xor(acc, o, 64);
        s[c] = acc * invt;
    }
    float m = s[0];
#pragma unroll
    for (int c = 1; c < Cq; ++c) m = fmaxf(m, s[c]);
    float e[Cq], denom = 0.f;
#pragma unroll
    for (int c = 0; c < Cq; ++c) { e[c] = expf(s[c] - m); denom += e[c]; }
    float inv = 1.f / (denom + 1e-8f);
#pragma unroll
    for (int j = 0; j < 3; ++j) {
        float4 acc = {0.f, 0.f, 0.f, 0.f};
#pragma unroll
        for (int c = 0; c < Cq; ++c) {
            acc.x += v4[c][j].x * e[c];
            acc.y += v4[c][j].y * e[c];
            acc.z += v4[c][j].z * e[c];
            acc.w += v4[c][j].w * e[c];
        }
        short4 o;
        o.x = ((__hip_bfloat16_raw)__float2bfloat16(acc.x * inv)).x;
        o.y = ((__hip_bfloat16_raw)__float2bfloat16(acc.y * inv)).x;
        o.z = ((__hip_bfloat16_raw)__float2bfloat16(acc.z * inv)).x;
        o.w = ((__hip_bfloat16_raw)__float2bfloat16(acc.w * inv)).x;
        *(short4*)((short*)g_pooledb + (size_t)seg * Dq + j * 256 + lane * 4) = o;
    }
}

// ---------- f = pooled @ W^T + b (UNnormalized) -> chunk-transposed fbt + row ssum ----------
__global__ __launch_bounds__(256) void fw_mfma_kernel(const float* __restrict__ bias) {
    __shared__ short lA[64 * 32];     // 4 KB
    __shared__ short lB[128 * 32];    // 8 KB
    __shared__ short ct[64][136];     // 17.4 KB; stride 136 shorts = 17 x 16B (b128-aligned)
    const int bm = blockIdx.y * 64;
    const int bn = blockIdx.x * 128;

    const int tid  = threadIdx.x;
    const int wave = tid >> 6, lane = tid & 63;
    const int wm = wave >> 1, wn = wave & 1;       // 2x2 wave grid; per-wave C: 32x64

    const short* A  = (const short*)g_pooledb;
    const short* Bt = (const short*)g_Wb;

    const int srow = lane >> 2;
    const int scol = (lane & 3) * 8;
    const int c0 = wave * 2, c1 = wave * 2 + 1;    // B chunks

    f32x4 acc[2][4];
#pragma unroll
    for (int m = 0; m < 2; ++m)
#pragma unroll
        for (int n = 0; n < 4; ++n) acc[m][n] = (f32x4){0.f, 0.f, 0.f, 0.f};

    for (int k0 = 0; k0 < Dq; k0 += 32) {
        GLDS16(A  + (size_t)(bm + wave * 16 + srow) * Dq + k0 + scol, lA + wave * 512);
        GLDS16(Bt + (size_t)(bn + c0 * 16 + srow) * Dq + k0 + scol, lB + c0 * 512);
        GLDS16(Bt + (size_t)(bn + c1 * 16 + srow) * Dq + k0 + scol, lB + c1 * 512);
        __syncthreads();

        bf16x8 af[2], bfr[4];
#pragma unroll
        for (int m = 0; m < 2; ++m) {
            int row = wm * 32 + m * 16 + (lane & 15);
            af[m] = *(const bf16x8*)(lA + row * 32 + (lane >> 4) * 8);
        }
#pragma unroll
        for (int n = 0; n < 4; ++n) {
            int row = wn * 64 + n * 16 + (lane & 15);
            bfr[n] = *(const bf16x8*)(lB + row * 32 + (lane >> 4) * 8);
        }
#pragma unroll
        for (int m = 0; m < 2; ++m)
#pragma unroll
            for (int n = 0; n < 4; ++n)
                acc[m][n] = __builtin_amdgcn_mfma_f32_16x16x32_bf16(af[m], bfr[n], acc[m][n], 0, 0, 0);
        __syncthreads();
    }

    // epilogue: bias-add -> LDS tile (bf16) + per-row sum-of-squares partials
    float ssp[2][4];
#pragma unroll
    for (int m = 0; m < 2; ++m)
#pragma unroll
        for (int j = 0; j < 4; ++j) ssp[m][j] = 0.f;
#pragma unroll
    for (int m = 0; m < 2; ++m) {
        int rloc = wm * 32 + m * 16 + (lane >> 4) * 4;
#pragma unroll
        for (int n = 0; n < 4; ++n) {
            int cloc = wn * 64 + n * 16 + (lane & 15);
            float bc = bias[bn + cloc];
#pragma unroll
            for (int j = 0; j < 4; ++j) {
                float x = acc[m][n][j] + bc;
                ct[rloc + j][cloc] = ((__hip_bfloat16_raw)__float2bfloat16(x)).x;
                ssp[m][j] += x * x;
            }
        }
    }
#pragma unroll
    for (int m = 0; m < 2; ++m)
#pragma unroll
        for (int j = 0; j < 4; ++j) {
#pragma unroll
            for (int o = 1; o < 16; o <<= 1) ssp[m][j] += __shfl_xor(ssp[m][j], o, 64);
        }
    if ((lane & 15) == 0) {
        int rbase = bm + wm * 32 + (lane >> 4) * 4;
#pragma unroll
        for (int m = 0; m < 2; ++m)
#pragma unroll
            for (int j = 0; j < 4; ++j)
                atomicAdd(&g_ssum[rbase + m * 16 + j], ssp[m][j]);
    }
    __syncthreads();

#pragma unroll
    for (int i = 0; i < 4; ++i) {
        int idx = i * 256 + tid;
        int r   = idx & 63;
        int chl = idx >> 6;               // 0..15
        bf16x8 val = *(const bf16x8*)&ct[r][chl * 8];
        *(bf16x8*)&g_fbt[((size_t)(bn / 8 + chl) * Nq + bm + r) * 8] = val;
    }
}

// ---------- sim = fb @ fb^T : 256x128 tile, BK=32, 48 KB LDS dbuf -> 2 blocks/CU ----------
// chunk addressing (shorts/8): A: buf*1536 + kc*256 + r (r<256); B: buf*1536 + 1024 + kc*128 + r (r<128)
#define STAGE_SIM(b, kt_) do {                                                              \
    _Pragma("unroll")                                                                       \
    for (int i = 0; i < 2; ++i) {                                                           \
        int g  = wave * 2 + i;                                                              \
        int kc = g >> 2, rb = g & 3;                                                        \
        GLDS16(fbt + ((size_t)((kt_) * 4 + kc) * Nq + bm + rb * 64 + lane) * 8,             \
               As + ((b) * 1536 + kc * 256 + rb * 64) * 8);                                 \
    }                                                                                       \
    {                                                                                       \
        int kcb = wave >> 1, rbb = wave & 1;                                                \
        GLDS16(fbt + ((size_t)((kt_) * 4 + kcb) * Nq + bn + rbb * 64 + lane) * 8,           \
               As + ((b) * 1536 + 1024 + kcb * 128 + rbb * 64) * 8);                        \
    }                                                                                       \
} while (0)

__global__ __launch_bounds__(512) void sim_mfma_kernel() {
    __shared__ short smem[2 * 1536 * 8];     // 48 KiB static -> 2+ blocks/CU
    short* As = smem;

    const int tid  = threadIdx.x;
    const int wave = tid >> 6, lane = tid & 63;
    const int wm = wave >> 1, wn = wave & 1;           // 4x2 wave grid; per-wave C: 64x64
    const int bm = blockIdx.y * 256, bn = blockIdx.x * 128;
    const short* fbt = g_fbt;

    f32x16 acc[2][2];
#pragma unroll
    for (int mi = 0; mi < 2; ++mi)
#pragma unroll
        for (int ni = 0; ni < 2; ++ni)
#pragma unroll
            for (int r = 0; r < 16; ++r) acc[mi][ni][r] = 0.f;

    STAGE_SIM(0, 0);

#pragma unroll 1
    for (int kt = 0; kt < 24; ++kt) {
        const int cur = kt & 1;
        if (kt < 23) {
            STAGE_SIM(cur ^ 1, kt + 1);
            asm volatile("s_waitcnt vmcnt(3)" ::: "memory");   // own 3 loads of tile kt done
        } else {
            asm volatile("s_waitcnt vmcnt(0)" ::: "memory");
        }
        __builtin_amdgcn_s_barrier();
        __builtin_amdgcn_sched_barrier(0);

        // BK=32 = 2 K-steps of 16; chunk kc = ks*2 + (lane>>5)
#pragma unroll
        for (int ks = 0; ks < 2; ++ks) {
            bf16x8 af[2], bfr[2];
            const int kc = ks * 2 + (lane >> 5);
#pragma unroll
            for (int mi = 0; mi < 2; ++mi)
                af[mi] = *(const bf16x8*)(As + (cur * 1536 + kc * 256 + wm * 64 + mi * 32 + (lane & 31)) * 8);
#pragma unroll
            for (int ni = 0; ni < 2; ++ni)
                bfr[ni] = *(const bf16x8*)(As + (cur * 1536 + 1024 + kc * 128 + wn * 64 + ni * 32 + (lane & 31)) * 8);
            __builtin_amdgcn_s_setprio(1);
#pragma unroll
            for (int mi = 0; mi < 2; ++mi)
#pragma unroll
                for (int ni = 0; ni < 2; ++ni)
                    acc[mi][ni] = __builtin_amdgcn_mfma_f32_32x32x16_bf16(af[mi], bfr[ni], acc[mi][ni], 0, 0, 0);
            __builtin_amdgcn_s_setprio(0);
        }
        __builtin_amdgcn_sched_barrier(0);
        __builtin_amdgcn_s_barrier();
    }

    // epilogue: normalize, fp16 store, violation count.
    // 32x32 C/D layout: col = lane&31, row = (reg&3) + 8*(reg>>2) + 4*(lane>>5)  [m74/m101]
    float rn_c[2];
#pragma unroll
    for (int ni = 0; ni < 2; ++ni) {
        int col = bn + wn * 64 + ni * 32 + (lane & 31);
        rn_c[ni] = rsqrtf(g_ssum[col]);
    }
    int vio = 0;
#pragma unroll
    for (int mi = 0; mi < 2; ++mi) {
        int rbase = bm + wm * 64 + mi * 32 + 4 * (lane >> 5);
        float rn_r[16];
#pragma unroll
        for (int r = 0; r < 16; ++r)
            rn_r[r] = rsqrtf(g_ssum[rbase + (r & 3) + 8 * (r >> 2)]);
#pragma unroll
        for (int ni = 0; ni < 2; ++ni) {
            int col = bn + wn * 64 + ni * 32 + (lane & 31);
#pragma unroll
            for (int r = 0; r < 16; ++r) {
                int row = rbase + (r & 3) + 8 * (r >> 2);
                float x = acc[mi][ni][r] * rn_r[r] * rn_c[ni];
                g_simh[(size_t)row * Nq + col] = (_Float16)x;
                vio += (x > 0.9f) && (((row ^ col) & 2047) != 0);
            }
        }
    }
#pragma unroll
    for (int o = 32; o > 0; o >>= 1) vio += __shfl_xor(vio, o, 64);
    if (lane == 0 && vio > 0) atomicAdd(&g_viol, (unsigned int)vio);
}

// ---------- per-row top-k logsumexp + fused mean (1 atomicAdd per block) ----------
__global__ __launch_bounds__(256) void lse_kernel(float* __restrict__ out) {
    const int tid = threadIdx.x;
    const int wave = tid >> 6, lane = tid & 63;
    const int row_id = blockIdx.x * 4 + wave;
    const _Float16* row = g_simh + (size_t)row_id * Nq;
    const int labi = row_id & 2047;
    const float invT = 1.0f / TEMPq;

    long long total = (long long)Nq * 4094LL - (long long)g_viol;
    int k = (int)(total / 8192LL);
    if (k < 1) k = 1;

    float v[64];
    float mx = -1e30f, mn = 1e30f;
    int cnt = 0;
#pragma unroll
    for (int q = 0; q < 8; ++q) {
        int j0 = q * 512 + lane * 8;
        f16x8 x8 = *(const f16x8*)(row + j0);
#pragma unroll
        for (int s = 0; s < 8; ++s) {
            int jj = q * 8 + s;
            int j  = j0 + s;
            float xv = (float)x8[s];
            bool sf = (xv <= 0.9f) && (((j ^ labi) & 2047) != 0);
            float val = sf ? xv : -2.0f;
            v[jj] = val;
            mx = fmaxf(mx, val);
            mn = fminf(mn, sf ? xv : 2.0f);
            cnt += (int)__popcll(__ballot(sf));
        }
    }
#pragma unroll
    for (int o = 32; o > 0; o >>= 1) {
        mx = fmaxf(mx, __shfl_xor(mx, o, 64));
        mn = fminf(mn, __shfl_xor(mn, o, 64));
    }

    const float pos = (float)row[(row_id + Bq) & (Nq - 1)];
    const float mxs = (cnt > 0) ? mx : -10.0f;
    const float ml  = fmaxf(pos, mxs) * invT;

    float lo = mn - 1e-3f, hi = mx;
    int c_hi = 0;
    const bool need = (cnt > k);
    if (need) {
        for (int it = 0; it < 9; ++it) {       // final bracket ~6e-4 -> loss err ~1e-3 << 0.166
            float mid = 0.5f * (lo + hi);
            int c = 0;
#pragma unroll
            for (int jj = 0; jj < 64; ++jj)
                c += (int)__popcll(__ballot(v[jj] > mid));
            if (c > k) lo = mid; else { hi = mid; c_hi = c; }
        }
    }

    float shi = 0.f, st = 0.f; int nt = 0;
#pragma unroll
    for (int jj = 0; jj < 64; ++jj) {
        float x = v[jj];
        float ev = __expf(x * invT - ml);
        if (!need)       { if (x > -1.5f) shi += ev; }
        else if (x > hi) { shi += ev; }
        else if (x > lo) { st += ev; nt++; }
    }
#pragma unroll
    for (int o = 32; o > 0; o >>= 1) {
        shi += __shfl_xor(shi, o, 64);
        st  += __shfl_xor(st,  o, 64);
        nt  += __shfl_xor(nt,  o, 64);
    }
    __shared__ float sblk[4];
    if (lane == 0) {
        float S = __expf(pos * invT - ml) + shi;
        if (need && c_hi < k && nt > 0)
            S += st * (float)(k - c_hi) / (float)nt;
        sblk[wave] = (logf(S) + ml) - pos * invT;
    }
    __syncthreads();
    if (tid == 0) {
        float bs = (sblk[0] + sblk[1] + sblk[2] + sblk[3]) * (1.0f / (float)Nq);
        atomicAdd(out, bs);
    }
}

extern "C" void kernel_launch(void* const* d_in, const int* in_sizes, int n_in,
                              void* d_out, int out_size, void* d_ws, size_t ws_size,
                              hipStream_t stream) {
    const float* z         = (const float*)d_in[0];
    const float* query     = (const float*)d_in[3];
    const float* attn_temp = (const float*)d_in[4];
    const float* W         = (const float*)d_in[5];
    const float* bias      = (const float*)d_in[6];
    float* out = (float*)d_out;

    prep_kernel<<<1024 + (Dq * Dq / 4) / 256, 256, 0, stream>>>(z, query, attn_temp, W, out);
    fw_mfma_kernel<<<dim3(Dq / 128, Nq / 64), 256, 0, stream>>>(bias);
    sim_mfma_kernel<<<dim3(32, 16), 512, 0, stream>>>();
    lse_kernel<<<Nq / 4, 256, 0, stream>>>(out);
}